// Round 4
// baseline (762.668 us; speedup 1.0000x reference)
//
#include <hip/hip_runtime.h>
#include <cmath>

#define B_ 64
#define L_ 200
#define H_ 128
#define S_ 64
#define E_ 256
#define K_ 101
#define NROW (B_ * L_)

__device__ __forceinline__ float wave_sum64(float v) {
#pragma unroll
  for (int o = 32; o > 0; o >>= 1) v += __shfl_xor(v, o, 64);
  return v;
}

__device__ __forceinline__ float block_sum_256(float v, volatile float* red) {
  v = wave_sum64(v);
  int w = threadIdx.x >> 6;
  __syncthreads();  // protect red reuse across calls
  if ((threadIdx.x & 63) == 0) red[w] = v;
  __syncthreads();
  return red[0] + red[1] + red[2] + red[3];
}

// x[b,l,h] = (item_emb[seq] + pos_emb[l]) * mask
__global__ void embed_kernel(const int* __restrict__ seqs, const float* __restrict__ emb,
                             const float* __restrict__ pos, float* __restrict__ x) {
  int r = blockIdx.x;          // b*L + l
  int h = threadIdx.x;         // 128
  int l = r % L_;
  int idx = seqs[r];
  float val = (idx != 0) ? (emb[(size_t)idx * H_ + h] + pos[l * H_ + h]) : 0.f;
  x[(size_t)r * H_ + h] = val;
}

// LayerNorm over H=128, one wave per row (2 elems/thread)
__global__ void ln_h_kernel(const float* __restrict__ x, const float* __restrict__ g,
                            const float* __restrict__ b, float* __restrict__ u) {
  int r = blockIdx.x;
  int t = threadIdx.x;  // 64
  float v0 = x[(size_t)r * H_ + t];
  float v1 = x[(size_t)r * H_ + 64 + t];
  float mean = wave_sum64(v0 + v1) * (1.f / 128.f);
  float d0 = v0 - mean, d1 = v1 - mean;
  float var = wave_sum64(d0 * d0 + d1 * d1) * (1.f / 128.f);
  float rs = rsqrtf(var + 1e-5f);
  u[(size_t)r * H_ + t]      = d0 * rs * g[t] + b[t];
  u[(size_t)r * H_ + 64 + t] = d1 * rs * g[64 + t] + b[64 + t];
}

// Final LN only at l = L-1, write xf[b,H]
__global__ void ln_final_kernel(const float* __restrict__ x, const float* __restrict__ g,
                                const float* __restrict__ b, float* __restrict__ xf) {
  int bb = blockIdx.x;
  int t = threadIdx.x;  // 64
  size_t r = (size_t)bb * L_ + (L_ - 1);
  float v0 = x[r * H_ + t];
  float v1 = x[r * H_ + 64 + t];
  float mean = wave_sum64(v0 + v1) * (1.f / 128.f);
  float d0 = v0 - mean, d1 = v1 - mean;
  float var = wave_sum64(d0 * d0 + d1 * d1) * (1.f / 128.f);
  float rs = rsqrtf(var + 1e-5f);
  xf[bb * H_ + t]      = d0 * rs * g[t] + b[t];
  xf[bb * H_ + 64 + t] = d1 * rs * g[64 + t] + b[64 + t];
}

// Tiled fp32 GEMM: C[M,N] = A[M,K] @ W[K,N] + bias
// EPI==1: C = (C_old + val) * mask[row]  (residual+mask epilogue)
template <int EPI>
__global__ __launch_bounds__(256) void gemm_kernel(
    const float* __restrict__ A, const float* __restrict__ W,
    const float* __restrict__ bias, float* __restrict__ C,
    int M, int N, int K, const int* __restrict__ seqs) {
  __shared__ float As[64][20];  // [m][k], pad to 20 for aligned float4 stores
  __shared__ float Bs[16][64];  // [k][n]
  const int tid = threadIdx.x;
  const int tx = tid & 15;   // n-dir
  const int ty = tid >> 4;   // m-dir
  const int m0 = blockIdx.y * 64;
  const int n0 = blockIdx.x * 64;

  const int a_m = tid >> 2;
  const int a_k = (tid & 3) << 2;
  const int b_k = tid >> 4;
  const int b_n = (tid & 15) << 2;

  float acc[4][4] = {{0.f, 0.f, 0.f, 0.f}, {0.f, 0.f, 0.f, 0.f},
                     {0.f, 0.f, 0.f, 0.f}, {0.f, 0.f, 0.f, 0.f}};

  for (int k0 = 0; k0 < K; k0 += 16) {
    float4 av = *(const float4*)(A + (size_t)(m0 + a_m) * K + k0 + a_k);
    float4 bv = *(const float4*)(W + (size_t)(b_k + k0) * N + n0 + b_n);
    *(float4*)&As[a_m][a_k] = av;
    *(float4*)&Bs[b_k][b_n] = bv;
    __syncthreads();
#pragma unroll
    for (int kk = 0; kk < 16; ++kk) {
      float4 b4 = *(const float4*)&Bs[kk][tx << 2];
      float a0 = As[ty * 4 + 0][kk];
      float a1 = As[ty * 4 + 1][kk];
      float a2 = As[ty * 4 + 2][kk];
      float a3 = As[ty * 4 + 3][kk];
      acc[0][0] += a0 * b4.x; acc[0][1] += a0 * b4.y; acc[0][2] += a0 * b4.z; acc[0][3] += a0 * b4.w;
      acc[1][0] += a1 * b4.x; acc[1][1] += a1 * b4.y; acc[1][2] += a1 * b4.z; acc[1][3] += a1 * b4.w;
      acc[2][0] += a2 * b4.x; acc[2][1] += a2 * b4.y; acc[2][2] += a2 * b4.z; acc[2][3] += a2 * b4.w;
      acc[3][0] += a3 * b4.x; acc[3][1] += a3 * b4.y; acc[3][2] += a3 * b4.z; acc[3][3] += a3 * b4.w;
    }
    __syncthreads();
  }

  float4 bz = *(const float4*)(bias + n0 + (tx << 2));
#pragma unroll
  for (int i = 0; i < 4; ++i) {
    int row = m0 + ty * 4 + i;
    float* cp = C + (size_t)row * N + n0 + (tx << 2);
    float4 val;
    val.x = acc[i][0] + bz.x;
    val.y = acc[i][1] + bz.y;
    val.z = acc[i][2] + bz.z;
    val.w = acc[i][3] + bz.w;
    if (EPI == 1) {
      float msk = (seqs[row] != 0) ? 1.f : 0.f;
      float4 old = *(const float4*)cp;
      val.x = (old.x + val.x) * msk;
      val.y = (old.y + val.y) * msk;
      val.z = (old.z + val.z) * msk;
      val.w = (old.w + val.w) * msk;
    }
    *(float4*)cp = val;
  }
}

// Depthwise conv (k=3, symmetric pad 1, cross-correlation) + bias + silu.
__global__ void conv_silu_kernel(const float* __restrict__ xz, const float* __restrict__ cw,
                                 const float* __restrict__ cb, float* __restrict__ xc,
                                 float* __restrict__ xsum) {
  __shared__ float red[4];
  int r = blockIdx.x;   // b*L + l
  int e = threadIdx.x;  // 256
  int l = r % L_;
  float w0 = cw[e * 3 + 0], w1 = cw[e * 3 + 1], w2 = cw[e * 3 + 2];
  float xm1 = (l > 0)      ? xz[(size_t)(r - 1) * 512 + e] : 0.f;
  float x0  =                xz[(size_t)r * 512 + e];
  float xp1 = (l < L_ - 1) ? xz[(size_t)(r + 1) * 512 + e] : 0.f;
  float v = w0 * xm1 + w1 * x0 + w2 * xp1 + cb[e];
  float sv = v / (1.f + expf(-v));  // silu
  xc[(size_t)r * E_ + e] = sv;
  float tot = block_sum_256(sv, red);
  if (threadIdx.x == 0) xsum[r] = tot;
}

// Sequential scan, collapsed state h[S] per batch.
// v4: producer-consumer wave specialization. Wave 0 (consumer) runs only the
// sequential matvec h <- M_t h + dBx (no exp, no barriers, no vmcnt drains).
// Waves 1-3 (producers) compute M_t = exp2(clip(d_i*A2_j)) into a 5-slot LDS
// ring, synced via LDS spin-flags. 16B granules XOR-swizzled so both the
// producer ds_write_b128 and consumer ds_read_b128 hit the conflict-minimal
// 8-lanes-per-bank-quad pattern.
__global__ __launch_bounds__(256, 1) void scan_kernel(
    const float* __restrict__ ssm,   // [B*L, 192]: delta_raw | Bm | Cm
    const float* __restrict__ xs,    // [B*L]
    const float* __restrict__ A_log, // [S] (block-offset applied by caller)
    float* __restrict__ hc_out) {    // [B*L, 64] per-lane h*C
  constexpr int RING = 5;
  __shared__ float Mring[RING][64][64];  // 80 KB
  __shared__ float auxd[RING][2][64];    // [0]=dBx, [1]=cm
  __shared__ float hshare[64];
  __shared__ float a2s[64];
  __shared__ int prod_flag[RING];
  __shared__ int cons_prog;

  const int b = blockIdx.x;
  const int tid = threadIdx.x;
  const int wave = tid >> 6;  // 0 = consumer, 1..3 = producers
  const int lane = tid & 63;
  const float LOG2E = 1.44269504088896340736f;
  const float LB = -14.4269504088896340736f;  // -10*log2e

  if (tid < RING) prod_flag[tid] = -1;
  if (tid == 0) cons_prog = -1;
  if (tid < 64) {
    hshare[tid] = 0.f;
    float al = fminf(fmaxf(A_log[tid], -5.f), 5.f);
    a2s[tid] = -expf(al) * LOG2E;
  }
  __syncthreads();  // only barrier in the kernel (before wave divergence)

  const float* base = ssm + (size_t)b * L_ * 192;
  const float* xsb = xs + b * L_;

  if (wave == 0) {
    // ---- consumer: the sequential chain ----
    float* hcb = hc_out + (size_t)b * L_ * 64;
    const int sw = lane & 15;
    for (int t = 0; t < L_; ++t) {
      const int slot = t % RING;
      volatile int* pf = &prod_flag[slot];
      while (*pf != t) { }
      float acc0 = auxd[slot][0][lane];  // dBx_i
      float cm   = auxd[slot][1][lane];
      float acc1 = 0.f, acc2 = 0.f, acc3 = 0.f;
#pragma unroll
      for (int p = 0; p < 16; ++p) {
        float4 m4 = *(const float4*)&Mring[slot][lane][p * 4];       // chunk c=p^sw
        float4 h4 = *(const float4*)&hshare[(p ^ sw) * 4];           // matching h chunk
        acc0 += m4.x * h4.x; acc1 += m4.y * h4.y;
        acc2 += m4.z * h4.z; acc3 += m4.w * h4.w;
      }
      float h = fminf(fmaxf((acc0 + acc1) + (acc2 + acc3), -100.f), 100.f);
      hshare[lane] = h;                       // same-wave RAW: DS pipe in-order
      hcb[(size_t)t * 64 + lane] = h * cm;    // fire-and-forget
      if (lane == 0) *(volatile int*)&cons_prog = t;  // after reads retired (in-order DS)
    }
  } else {
    // ---- producers: h-independent exp matrices, 3 waves round-robin over t ----
    float a2v[64];
#pragma unroll
    for (int g = 0; g < 16; ++g) {
      float4 q = *(const float4*)&a2s[g * 4];
      a2v[g * 4 + 0] = q.x; a2v[g * 4 + 1] = q.y;
      a2v[g * 4 + 2] = q.z; a2v[g * 4 + 3] = q.w;
    }
    volatile int* cp = &cons_prog;
    const int sw = lane & 15;
    for (int t = wave - 1; t < L_; t += 3) {
      const int slot = t % RING;
      // issue global loads before the spin; consumed after (latency hidden)
      float dr  = base[(size_t)t * 192 + lane];
      float bm  = base[(size_t)t * 192 + 64 + lane];
      float cm  = base[(size_t)t * 192 + 128 + lane];
      float xst = xsb[t];
      while (*cp < t - RING) { }  // slot free once consumer finished t-RING
      float d = fmaxf(dr, 0.f) + log1pf(__expf(-fabsf(dr)));  // softplus
#pragma unroll
      for (int c = 0; c < 16; ++c) {
        float4 e;
        e.x = __builtin_amdgcn_exp2f(fmaxf(d * a2v[c * 4 + 0], LB));
        e.y = __builtin_amdgcn_exp2f(fmaxf(d * a2v[c * 4 + 1], LB));
        e.z = __builtin_amdgcn_exp2f(fmaxf(d * a2v[c * 4 + 2], LB));
        e.w = __builtin_amdgcn_exp2f(fmaxf(d * a2v[c * 4 + 3], LB));
        *(float4*)&Mring[slot][lane][(c ^ sw) * 4] = e;  // swizzled granule
      }
      auxd[slot][0][lane] = d * bm * xst;
      auxd[slot][1][lane] = cm;
      __threadfence_block();  // data writes drain before flag
      if (lane == 0) *(volatile int*)&prod_flag[slot] = t;
    }
  }
}

// s = sum(hc row); y = s + D*xc ; yln = LN_E(y) ; v = yln * silu(z)
// v may alias xc (each thread reads xc[r,e] before writing v[r,e]).
__global__ void gate_kernel(const float* __restrict__ hc, const float* __restrict__ xc,
                            const float* __restrict__ xz, const float* __restrict__ D,
                            const float* __restrict__ g, const float* __restrict__ bb,
                            float* __restrict__ v) {
  __shared__ float red[4];
  int r = blockIdx.x;
  int e = threadIdx.x;  // 256
  // each wave redundantly reduces the 64 hc values
  float s = wave_sum64(hc[(size_t)r * 64 + (e & 63)]);
  float y = s + D[e] * xc[(size_t)r * E_ + e];
  float mean = block_sum_256(y, red) * (1.f / 256.f);
  float d = y - mean;
  float var = block_sum_256(d * d, red) * (1.f / 256.f);
  float yln = d * rsqrtf(var + 1e-5f) * g[e] + bb[e];
  float z = xz[(size_t)r * 512 + 256 + e];
  v[(size_t)r * E_ + e] = yln * (z / (1.f + expf(-z)));
}

// logits[b,k] = xf[b,:] . item_emb[item_idxs[b,k], :]
__global__ void logits_kernel(const float* __restrict__ xf, const int* __restrict__ idxs,
                              const float* __restrict__ emb, float* __restrict__ out) {
  int p = blockIdx.x;  // b*K + k
  int b = p / K_;
  int t = threadIdx.x;  // 64
  int id = idxs[p];
  float a = xf[b * H_ + t] * emb[(size_t)id * H_ + t] +
            xf[b * H_ + 64 + t] * emb[(size_t)id * H_ + 64 + t];
  a = wave_sum64(a);
  if (t == 0) out[p] = a;
}

extern "C" void kernel_launch(void* const* d_in, const int* in_sizes, int n_in,
                              void* d_out, int out_size, void* d_ws, size_t ws_size,
                              hipStream_t stream) {
  const int*   seqs   = (const int*)d_in[0];
  const int*   idxs   = (const int*)d_in[1];
  const float* emb    = (const float*)d_in[2];
  const float* pos    = (const float*)d_in[3];
  const float* blk_g  = (const float*)d_in[4];
  const float* blk_b  = (const float*)d_in[5];
  const float* in_w   = (const float*)d_in[6];
  const float* in_b   = (const float*)d_in[7];
  const float* conv_w = (const float*)d_in[8];
  const float* conv_b = (const float*)d_in[9];
  const float* xp_w   = (const float*)d_in[10];
  const float* xp_b   = (const float*)d_in[11];
  const float* A_log  = (const float*)d_in[12];
  const float* D_p    = (const float*)d_in[13];
  const float* out_w  = (const float*)d_in[14];
  const float* out_b  = (const float*)d_in[15];
  const float* ig     = (const float*)d_in[16];
  const float* ib     = (const float*)d_in[17];
  const float* fg     = (const float*)d_in[18];
  const float* fb     = (const float*)d_in[19];
  float* out = (float*)d_out;
  float* ws = (float*)d_ws;

  // workspace layout (floats); v aliases xc (in-place gate). ~65.6 MB total.
  float* x   = ws;               // [12800,128]
  float* u   = ws + 1638400;     // [12800,128]
  float* xz  = ws + 3276800;     // [12800,512]
  float* xc  = ws + 9830400;     // [12800,256]
  float* ssm = ws + 13107200;    // [12800,192]
  float* xs  = ws + 15564800;    // [12800]
  float* hc  = ws + 15577600;    // [12800,64]
  float* xf  = ws + 16396800;    // [64,128]
  float* v   = xc;               // in-place

  embed_kernel<<<NROW, 128, 0, stream>>>(seqs, emb, pos, x);

  for (int blk = 0; blk < 2; ++blk) {
    ln_h_kernel<<<NROW, 64, 0, stream>>>(x, blk_g + blk * H_, blk_b + blk * H_, u);
    gemm_kernel<0><<<dim3(512 / 64, NROW / 64), 256, 0, stream>>>(
        u, in_w + (size_t)blk * H_ * 2 * E_, in_b + blk * 2 * E_, xz, NROW, 512, 128, nullptr);
    conv_silu_kernel<<<NROW, 256, 0, stream>>>(xz, conv_w + blk * E_ * 3, conv_b + blk * E_,
                                               xc, xs);
    gemm_kernel<0><<<dim3(192 / 64, NROW / 64), 256, 0, stream>>>(
        xc, xp_w + (size_t)blk * E_ * 3 * S_, xp_b + blk * 3 * S_, ssm, NROW, 192, 256, nullptr);
    scan_kernel<<<B_, 256, 0, stream>>>(ssm, xs, A_log + blk * S_, hc);
    gate_kernel<<<NROW, 256, 0, stream>>>(hc, xc, xz, D_p + blk * E_, ig + blk * E_,
                                          ib + blk * E_, v);
    gemm_kernel<1><<<dim3(128 / 64, NROW / 64), 256, 0, stream>>>(
        v, out_w + (size_t)blk * E_ * H_, out_b + blk * H_, x, NROW, 128, 256, seqs);
  }

  ln_final_kernel<<<B_, 64, 0, stream>>>(x, fg, fb, xf);
  logits_kernel<<<B_ * K_, 64, 0, stream>>>(xf, idxs, emb, out);
}

// Round 5
// 629.360 us; speedup vs baseline: 1.2118x; 1.2118x over previous
//
#include <hip/hip_runtime.h>
#include <cmath>

#define B_ 64
#define L_ 200
#define H_ 128
#define S_ 64
#define E_ 256
#define K_ 101
#define NROW (B_ * L_)

__device__ __forceinline__ float wave_sum64(float v) {
#pragma unroll
  for (int o = 32; o > 0; o >>= 1) v += __shfl_xor(v, o, 64);
  return v;
}

__device__ __forceinline__ float block_sum_256(float v, volatile float* red) {
  v = wave_sum64(v);
  int w = threadIdx.x >> 6;
  __syncthreads();  // protect red reuse across calls
  if ((threadIdx.x & 63) == 0) red[w] = v;
  __syncthreads();
  return red[0] + red[1] + red[2] + red[3];
}

// x[b,l,h] = (item_emb[seq] + pos_emb[l]) * mask
__global__ void embed_kernel(const int* __restrict__ seqs, const float* __restrict__ emb,
                             const float* __restrict__ pos, float* __restrict__ x) {
  int r = blockIdx.x;          // b*L + l
  int h = threadIdx.x;         // 128
  int l = r % L_;
  int idx = seqs[r];
  float val = (idx != 0) ? (emb[(size_t)idx * H_ + h] + pos[l * H_ + h]) : 0.f;
  x[(size_t)r * H_ + h] = val;
}

// LayerNorm over H=128, one wave per row (2 elems/thread)
__global__ void ln_h_kernel(const float* __restrict__ x, const float* __restrict__ g,
                            const float* __restrict__ b, float* __restrict__ u) {
  int r = blockIdx.x;
  int t = threadIdx.x;  // 64
  float v0 = x[(size_t)r * H_ + t];
  float v1 = x[(size_t)r * H_ + 64 + t];
  float mean = wave_sum64(v0 + v1) * (1.f / 128.f);
  float d0 = v0 - mean, d1 = v1 - mean;
  float var = wave_sum64(d0 * d0 + d1 * d1) * (1.f / 128.f);
  float rs = rsqrtf(var + 1e-5f);
  u[(size_t)r * H_ + t]      = d0 * rs * g[t] + b[t];
  u[(size_t)r * H_ + 64 + t] = d1 * rs * g[64 + t] + b[64 + t];
}

// Final LN only at l = L-1, write xf[b,H]
__global__ void ln_final_kernel(const float* __restrict__ x, const float* __restrict__ g,
                                const float* __restrict__ b, float* __restrict__ xf) {
  int bb = blockIdx.x;
  int t = threadIdx.x;  // 64
  size_t r = (size_t)bb * L_ + (L_ - 1);
  float v0 = x[r * H_ + t];
  float v1 = x[r * H_ + 64 + t];
  float mean = wave_sum64(v0 + v1) * (1.f / 128.f);
  float d0 = v0 - mean, d1 = v1 - mean;
  float var = wave_sum64(d0 * d0 + d1 * d1) * (1.f / 128.f);
  float rs = rsqrtf(var + 1e-5f);
  xf[bb * H_ + t]      = d0 * rs * g[t] + b[t];
  xf[bb * H_ + 64 + t] = d1 * rs * g[64 + t] + b[64 + t];
}

// Tiled fp32 GEMM: C[M,N] = A[M,K] @ W[K,N] + bias
// EPI==1: C = (C_old + val) * mask[row]  (residual+mask epilogue)
template <int EPI>
__global__ __launch_bounds__(256) void gemm_kernel(
    const float* __restrict__ A, const float* __restrict__ W,
    const float* __restrict__ bias, float* __restrict__ C,
    int M, int N, int K, const int* __restrict__ seqs) {
  __shared__ float As[64][20];  // [m][k], pad to 20 for aligned float4 stores
  __shared__ float Bs[16][64];  // [k][n]
  const int tid = threadIdx.x;
  const int tx = tid & 15;   // n-dir
  const int ty = tid >> 4;   // m-dir
  const int m0 = blockIdx.y * 64;
  const int n0 = blockIdx.x * 64;

  const int a_m = tid >> 2;
  const int a_k = (tid & 3) << 2;
  const int b_k = tid >> 4;
  const int b_n = (tid & 15) << 2;

  float acc[4][4] = {{0.f, 0.f, 0.f, 0.f}, {0.f, 0.f, 0.f, 0.f},
                     {0.f, 0.f, 0.f, 0.f}, {0.f, 0.f, 0.f, 0.f}};

  for (int k0 = 0; k0 < K; k0 += 16) {
    float4 av = *(const float4*)(A + (size_t)(m0 + a_m) * K + k0 + a_k);
    float4 bv = *(const float4*)(W + (size_t)(b_k + k0) * N + n0 + b_n);
    *(float4*)&As[a_m][a_k] = av;
    *(float4*)&Bs[b_k][b_n] = bv;
    __syncthreads();
#pragma unroll
    for (int kk = 0; kk < 16; ++kk) {
      float4 b4 = *(const float4*)&Bs[kk][tx << 2];
      float a0 = As[ty * 4 + 0][kk];
      float a1 = As[ty * 4 + 1][kk];
      float a2 = As[ty * 4 + 2][kk];
      float a3 = As[ty * 4 + 3][kk];
      acc[0][0] += a0 * b4.x; acc[0][1] += a0 * b4.y; acc[0][2] += a0 * b4.z; acc[0][3] += a0 * b4.w;
      acc[1][0] += a1 * b4.x; acc[1][1] += a1 * b4.y; acc[1][2] += a1 * b4.z; acc[1][3] += a1 * b4.w;
      acc[2][0] += a2 * b4.x; acc[2][1] += a2 * b4.y; acc[2][2] += a2 * b4.z; acc[2][3] += a2 * b4.w;
      acc[3][0] += a3 * b4.x; acc[3][1] += a3 * b4.y; acc[3][2] += a3 * b4.z; acc[3][3] += a3 * b4.w;
    }
    __syncthreads();
  }

  float4 bz = *(const float4*)(bias + n0 + (tx << 2));
#pragma unroll
  for (int i = 0; i < 4; ++i) {
    int row = m0 + ty * 4 + i;
    float* cp = C + (size_t)row * N + n0 + (tx << 2);
    float4 val;
    val.x = acc[i][0] + bz.x;
    val.y = acc[i][1] + bz.y;
    val.z = acc[i][2] + bz.z;
    val.w = acc[i][3] + bz.w;
    if (EPI == 1) {
      float msk = (seqs[row] != 0) ? 1.f : 0.f;
      float4 old = *(const float4*)cp;
      val.x = (old.x + val.x) * msk;
      val.y = (old.y + val.y) * msk;
      val.z = (old.z + val.z) * msk;
      val.w = (old.w + val.w) * msk;
    }
    *(float4*)cp = val;
  }
}

// Depthwise conv (k=3, symmetric pad 1, cross-correlation) + bias + silu.
__global__ void conv_silu_kernel(const float* __restrict__ xz, const float* __restrict__ cw,
                                 const float* __restrict__ cb, float* __restrict__ xc,
                                 float* __restrict__ xsum) {
  __shared__ float red[4];
  int r = blockIdx.x;   // b*L + l
  int e = threadIdx.x;  // 256
  int l = r % L_;
  float w0 = cw[e * 3 + 0], w1 = cw[e * 3 + 1], w2 = cw[e * 3 + 2];
  float xm1 = (l > 0)      ? xz[(size_t)(r - 1) * 512 + e] : 0.f;
  float x0  =                xz[(size_t)r * 512 + e];
  float xp1 = (l < L_ - 1) ? xz[(size_t)(r + 1) * 512 + e] : 0.f;
  float v = w0 * xm1 + w1 * x0 + w2 * xp1 + cb[e];
  float sv = v / (1.f + expf(-v));  // silu
  xc[(size_t)r * E_ + e] = sv;
  float tot = block_sum_256(sv, red);
  if (threadIdx.x == 0) xsum[r] = tot;
}

// Sequential scan, collapsed state h[S] per batch.
// v5: producer-consumer wave specialization (as v4) with conflict-free LDS:
//  - Mring rows padded to 68 floats: lane i chunk p hits bank-group 4*((i+p)%8)
//    -> 8 lanes per 4-bank group = the wave64-b128 hardware minimum, balanced.
//  - no XOR swizzle: consumer h-chunk read is a same-address broadcast (free).
//  - producer ring-full spin throttled with s_sleep to free LDS issue slots.
__global__ __launch_bounds__(256, 1) void scan_kernel(
    const float* __restrict__ ssm,   // [B*L, 192]: delta_raw | Bm | Cm
    const float* __restrict__ xs,    // [B*L]
    const float* __restrict__ A_log, // [S] (block-offset applied by caller)
    float* __restrict__ hc_out) {    // [B*L, 64] per-lane h*C
  constexpr int RING = 5;
  __shared__ float Mring[RING][64][68];  // padded rows; ~85 KB
  __shared__ float auxd[RING][2][64];    // [0]=dBx, [1]=cm
  __shared__ float hshare[64];
  __shared__ float a2s[64];
  __shared__ int prod_flag[RING];
  __shared__ int cons_prog;

  const int b = blockIdx.x;
  const int tid = threadIdx.x;
  const int wave = tid >> 6;  // 0 = consumer, 1..3 = producers
  const int lane = tid & 63;
  const float LOG2E = 1.44269504088896340736f;
  const float LB = -14.4269504088896340736f;  // -10*log2e

  if (tid < RING) prod_flag[tid] = -1;
  if (tid == 0) cons_prog = -1;
  if (tid < 64) {
    hshare[tid] = 0.f;
    float al = fminf(fmaxf(A_log[tid], -5.f), 5.f);
    a2s[tid] = -expf(al) * LOG2E;
  }
  __syncthreads();  // only barrier in the kernel (before wave divergence)

  const float* base = ssm + (size_t)b * L_ * 192;
  const float* xsb = xs + b * L_;

  if (wave == 0) {
    // ---- consumer: the sequential chain ----
    float* hcb = hc_out + (size_t)b * L_ * 64;
    for (int t = 0; t < L_; ++t) {
      const int slot = t % RING;
      volatile int* pf = &prod_flag[slot];
      while (*pf != t) { }
      float acc0 = auxd[slot][0][lane];  // dBx_i
      float cm   = auxd[slot][1][lane];
      float acc1 = 0.f, acc2 = 0.f, acc3 = 0.f;
#pragma unroll
      for (int p = 0; p < 16; ++p) {
        float4 m4 = *(const float4*)&Mring[slot][lane][p * 4];  // balanced b128
        float4 h4 = *(const float4*)&hshare[p * 4];             // broadcast (free)
        acc0 += m4.x * h4.x; acc1 += m4.y * h4.y;
        acc2 += m4.z * h4.z; acc3 += m4.w * h4.w;
      }
      float h = fminf(fmaxf((acc0 + acc1) + (acc2 + acc3), -100.f), 100.f);
      hshare[lane] = h;                       // same-wave RAW: DS pipe in-order
      hcb[(size_t)t * 64 + lane] = h * cm;    // fire-and-forget
      if (lane == 0) *(volatile int*)&cons_prog = t;  // after reads retired (in-order DS)
    }
  } else {
    // ---- producers: h-independent exp matrices, 3 waves round-robin over t ----
    float a2v[64];
#pragma unroll
    for (int g = 0; g < 16; ++g) {
      float4 q = *(const float4*)&a2s[g * 4];
      a2v[g * 4 + 0] = q.x; a2v[g * 4 + 1] = q.y;
      a2v[g * 4 + 2] = q.z; a2v[g * 4 + 3] = q.w;
    }
    volatile int* cp = &cons_prog;
    for (int t = wave - 1; t < L_; t += 3) {
      const int slot = t % RING;
      // issue global loads before the spin; consumed after (latency hidden)
      float dr  = base[(size_t)t * 192 + lane];
      float bm  = base[(size_t)t * 192 + 64 + lane];
      float cm  = base[(size_t)t * 192 + 128 + lane];
      float xst = xsb[t];
      while (*cp < t - RING) { __builtin_amdgcn_s_sleep(1); }  // ring full: throttle
      float d = fmaxf(dr, 0.f) + log1pf(__expf(-fabsf(dr)));   // softplus
#pragma unroll
      for (int c = 0; c < 16; ++c) {
        float4 e;
        e.x = __builtin_amdgcn_exp2f(fmaxf(d * a2v[c * 4 + 0], LB));
        e.y = __builtin_amdgcn_exp2f(fmaxf(d * a2v[c * 4 + 1], LB));
        e.z = __builtin_amdgcn_exp2f(fmaxf(d * a2v[c * 4 + 2], LB));
        e.w = __builtin_amdgcn_exp2f(fmaxf(d * a2v[c * 4 + 3], LB));
        *(float4*)&Mring[slot][lane][c * 4] = e;  // balanced b128 (padded rows)
      }
      auxd[slot][0][lane] = d * bm * xst;
      auxd[slot][1][lane] = cm;
      __threadfence_block();  // data writes drain before flag
      if (lane == 0) *(volatile int*)&prod_flag[slot] = t;
    }
  }
}

// s = sum(hc row); y = s + D*xc ; yln = LN_E(y) ; v = yln * silu(z)
// v may alias xc (each thread reads xc[r,e] before writing v[r,e]).
__global__ void gate_kernel(const float* __restrict__ hc, const float* __restrict__ xc,
                            const float* __restrict__ xz, const float* __restrict__ D,
                            const float* __restrict__ g, const float* __restrict__ bb,
                            float* __restrict__ v) {
  __shared__ float red[4];
  int r = blockIdx.x;
  int e = threadIdx.x;  // 256
  // each wave redundantly reduces the 64 hc values
  float s = wave_sum64(hc[(size_t)r * 64 + (e & 63)]);
  float y = s + D[e] * xc[(size_t)r * E_ + e];
  float mean = block_sum_256(y, red) * (1.f / 256.f);
  float d = y - mean;
  float var = block_sum_256(d * d, red) * (1.f / 256.f);
  float yln = d * rsqrtf(var + 1e-5f) * g[e] + bb[e];
  float z = xz[(size_t)r * 512 + 256 + e];
  v[(size_t)r * E_ + e] = yln * (z / (1.f + expf(-z)));
}

// logits[b,k] = xf[b,:] . item_emb[item_idxs[b,k], :]
__global__ void logits_kernel(const float* __restrict__ xf, const int* __restrict__ idxs,
                              const float* __restrict__ emb, float* __restrict__ out) {
  int p = blockIdx.x;  // b*K + k
  int b = p / K_;
  int t = threadIdx.x;  // 64
  int id = idxs[p];
  float a = xf[b * H_ + t] * emb[(size_t)id * H_ + t] +
            xf[b * H_ + 64 + t] * emb[(size_t)id * H_ + 64 + t];
  a = wave_sum64(a);
  if (t == 0) out[p] = a;
}

extern "C" void kernel_launch(void* const* d_in, const int* in_sizes, int n_in,
                              void* d_out, int out_size, void* d_ws, size_t ws_size,
                              hipStream_t stream) {
  const int*   seqs   = (const int*)d_in[0];
  const int*   idxs   = (const int*)d_in[1];
  const float* emb    = (const float*)d_in[2];
  const float* pos    = (const float*)d_in[3];
  const float* blk_g  = (const float*)d_in[4];
  const float* blk_b  = (const float*)d_in[5];
  const float* in_w   = (const float*)d_in[6];
  const float* in_b   = (const float*)d_in[7];
  const float* conv_w = (const float*)d_in[8];
  const float* conv_b = (const float*)d_in[9];
  const float* xp_w   = (const float*)d_in[10];
  const float* xp_b   = (const float*)d_in[11];
  const float* A_log  = (const float*)d_in[12];
  const float* D_p    = (const float*)d_in[13];
  const float* out_w  = (const float*)d_in[14];
  const float* out_b  = (const float*)d_in[15];
  const float* ig     = (const float*)d_in[16];
  const float* ib     = (const float*)d_in[17];
  const float* fg     = (const float*)d_in[18];
  const float* fb     = (const float*)d_in[19];
  float* out = (float*)d_out;
  float* ws = (float*)d_ws;

  // workspace layout (floats); v aliases xc (in-place gate). ~65.6 MB total.
  float* x   = ws;               // [12800,128]
  float* u   = ws + 1638400;     // [12800,128]
  float* xz  = ws + 3276800;     // [12800,512]
  float* xc  = ws + 9830400;     // [12800,256]
  float* ssm = ws + 13107200;    // [12800,192]
  float* xs  = ws + 15564800;    // [12800]
  float* hc  = ws + 15577600;    // [12800,64]
  float* xf  = ws + 16396800;    // [64,128]
  float* v   = xc;               // in-place

  embed_kernel<<<NROW, 128, 0, stream>>>(seqs, emb, pos, x);

  for (int blk = 0; blk < 2; ++blk) {
    ln_h_kernel<<<NROW, 64, 0, stream>>>(x, blk_g + blk * H_, blk_b + blk * H_, u);
    gemm_kernel<0><<<dim3(512 / 64, NROW / 64), 256, 0, stream>>>(
        u, in_w + (size_t)blk * H_ * 2 * E_, in_b + blk * 2 * E_, xz, NROW, 512, 128, nullptr);
    conv_silu_kernel<<<NROW, 256, 0, stream>>>(xz, conv_w + blk * E_ * 3, conv_b + blk * E_,
                                               xc, xs);
    gemm_kernel<0><<<dim3(192 / 64, NROW / 64), 256, 0, stream>>>(
        xc, xp_w + (size_t)blk * E_ * 3 * S_, xp_b + blk * 3 * S_, ssm, NROW, 192, 256, nullptr);
    scan_kernel<<<B_, 256, 0, stream>>>(ssm, xs, A_log + blk * S_, hc);
    gate_kernel<<<NROW, 256, 0, stream>>>(hc, xc, xz, D_p + blk * E_, ig + blk * E_,
                                          ib + blk * E_, v);
    gemm_kernel<1><<<dim3(128 / 64, NROW / 64), 256, 0, stream>>>(
        v, out_w + (size_t)blk * E_ * H_, out_b + blk * H_, x, NROW, 128, 256, seqs);
  }

  ln_final_kernel<<<B_, 64, 0, stream>>>(x, fg, fb, xf);
  logits_kernel<<<B_ * K_, 64, 0, stream>>>(xf, idxs, emb, out);
}

// Round 7
// 224.513 us; speedup vs baseline: 3.3970x; 2.8032x over previous
//
#include <hip/hip_runtime.h>
#include <hip/hip_bf16.h>
#include <cmath>

#define B_ 64
#define L_ 200
#define H_ 128
#define E_ 256
#define K_ 101
#define NROW (B_ * L_)

using short8 = __attribute__((ext_vector_type(8))) short;
using f32x4  = __attribute__((ext_vector_type(4))) float;

__device__ __forceinline__ float wave_sum64(float v) {
#pragma unroll
  for (int o = 32; o > 0; o >>= 1) v += __shfl_xor(v, o, 64);
  return v;
}

__device__ __forceinline__ float block_sum_256(float v, volatile float* red) {
  v = wave_sum64(v);
  int w = threadIdx.x >> 6;
  __syncthreads();  // protect red reuse across calls
  if ((threadIdx.x & 63) == 0) red[w] = v;
  __syncthreads();
  return red[0] + red[1] + red[2] + red[3];
}

// x[b,l,h] = (item_emb[seq] + pos_emb[l]) * mask
__global__ void embed_kernel(const int* __restrict__ seqs, const float* __restrict__ emb,
                             const float* __restrict__ pos, float* __restrict__ x) {
  int r = blockIdx.x;          // b*L + l
  int h = threadIdx.x;         // 128
  int l = r % L_;
  int idx = seqs[r];
  float val = (idx != 0) ? (emb[(size_t)idx * H_ + h] + pos[l * H_ + h]) : 0.f;
  x[(size_t)r * H_ + h] = val;
}

// LayerNorm over H=128, one wave per row; bf16 output (feeds MFMA GEMM)
__global__ void ln_h_kernel(const float* __restrict__ x, const float* __restrict__ g,
                            const float* __restrict__ b, __hip_bfloat16* __restrict__ u) {
  int r = blockIdx.x;
  int t = threadIdx.x;  // 64
  float v0 = x[(size_t)r * H_ + t];
  float v1 = x[(size_t)r * H_ + 64 + t];
  float mean = wave_sum64(v0 + v1) * (1.f / 128.f);
  float d0 = v0 - mean, d1 = v1 - mean;
  float var = wave_sum64(d0 * d0 + d1 * d1) * (1.f / 128.f);
  float rs = rsqrtf(var + 1e-5f);
  u[(size_t)r * H_ + t]      = __float2bfloat16(d0 * rs * g[t] + b[t]);
  u[(size_t)r * H_ + 64 + t] = __float2bfloat16(d1 * rs * g[64 + t] + b[64 + t]);
}

// Final LN only at l = L-1, write xf[b,H] (fp32)
__global__ void ln_final_kernel(const float* __restrict__ x, const float* __restrict__ g,
                                const float* __restrict__ b, float* __restrict__ xf) {
  int bb = blockIdx.x;
  int t = threadIdx.x;  // 64
  size_t r = (size_t)bb * L_ + (L_ - 1);
  float v0 = x[r * H_ + t];
  float v1 = x[r * H_ + 64 + t];
  float mean = wave_sum64(v0 + v1) * (1.f / 128.f);
  float d0 = v0 - mean, d1 = v1 - mean;
  float var = wave_sum64(d0 * d0 + d1 * d1) * (1.f / 128.f);
  float rs = rsqrtf(var + 1e-5f);
  xf[bb * H_ + t]      = d0 * rs * g[t] + b[t];
  xf[bb * H_ + 64 + t] = d1 * rs * g[64 + t] + b[64 + t];
}

// Weight transpose + bf16 cast: W fp32 [K][N] -> Wt bf16 [N][K]; blockIdx.z = blk.
__global__ void wtrans_kernel(const float* __restrict__ W, __hip_bfloat16* __restrict__ Wt,
                              int K, int N) {
  __shared__ float ts[64][65];
  const float* Wb = W + (size_t)blockIdx.z * K * N;
  __hip_bfloat16* Wtb = Wt + (size_t)blockIdx.z * K * N;
  int n0 = blockIdx.x * 64, k0 = blockIdx.y * 64;
  int c = threadIdx.x & 63, r4 = threadIdx.x >> 6;
#pragma unroll
  for (int i = 0; i < 16; ++i) {
    int row = r4 * 16 + i;
    ts[row][c] = Wb[(size_t)(k0 + row) * N + n0 + c];
  }
  __syncthreads();
#pragma unroll
  for (int i = 0; i < 16; ++i) {
    int nrow = r4 * 16 + i;
    Wtb[(size_t)(n0 + nrow) * K + k0 + c] = __float2bfloat16(ts[c][nrow]);
  }
}

// bf16 MFMA GEMM: C[M,N] = A[M,K] @ Wt[N,K]^T + bias.
// EPI==0: bf16 output to Ch.  EPI==1: fp32 residual C=(C_old+val)*mask to Cf.
// 64x64 tile, 4 waves in 2x2 grid, each 32x32 via 2x2 mfma_f32_16x16x32_bf16.
// Layouts (guide-verified): A-frag A[m=lane&15][k=quad*8+j]; B-frag from Wt rows
// (same pattern with n=lane&15); D: row=quad*4+reg, col=lane&15.
template <int EPI>
__global__ __launch_bounds__(256) void gemm_bf16_kernel(
    const __hip_bfloat16* __restrict__ A, const __hip_bfloat16* __restrict__ Wt,
    const float* __restrict__ bias, float* __restrict__ Cf,
    __hip_bfloat16* __restrict__ Ch, int M, int N, int K,
    const int* __restrict__ seqs) {
  __shared__ __align__(16) short As[64][72];  // rows padded to 144 B (2-way max)
  __shared__ __align__(16) short Ws[64][72];
  const int tid = threadIdx.x;
  const int wid = tid >> 6, lane = tid & 63;
  const int wm = (wid >> 1) * 32, wn = (wid & 1) * 32;
  const int quad = lane >> 4, l16 = lane & 15;
  const int m0 = blockIdx.y * 64, n0 = blockIdx.x * 64;
  const int srow = tid >> 3, sseg = (tid & 7) * 8;  // staging: 32 rows x 8 segs
  const short* Ag = (const short*)A;
  const short* Wg = (const short*)Wt;

  f32x4 acc[2][2] = {{{0.f, 0.f, 0.f, 0.f}, {0.f, 0.f, 0.f, 0.f}},
                     {{0.f, 0.f, 0.f, 0.f}, {0.f, 0.f, 0.f, 0.f}}};

  for (int k0 = 0; k0 < K; k0 += 64) {
    __syncthreads();  // WAR: previous frag reads done before restage
    *(short8*)&As[srow][sseg]      = *(const short8*)&Ag[(size_t)(m0 + srow) * K + k0 + sseg];
    *(short8*)&As[srow + 32][sseg] = *(const short8*)&Ag[(size_t)(m0 + srow + 32) * K + k0 + sseg];
    *(short8*)&Ws[srow][sseg]      = *(const short8*)&Wg[(size_t)(n0 + srow) * K + k0 + sseg];
    *(short8*)&Ws[srow + 32][sseg] = *(const short8*)&Wg[(size_t)(n0 + srow + 32) * K + k0 + sseg];
    __syncthreads();  // RAW
#pragma unroll
    for (int kb = 0; kb < 2; ++kb) {
      short8 a0 = *(const short8*)&As[wm + l16][kb * 32 + quad * 8];
      short8 a1 = *(const short8*)&As[wm + 16 + l16][kb * 32 + quad * 8];
      short8 b0 = *(const short8*)&Ws[wn + l16][kb * 32 + quad * 8];
      short8 b1 = *(const short8*)&Ws[wn + 16 + l16][kb * 32 + quad * 8];
      acc[0][0] = __builtin_amdgcn_mfma_f32_16x16x32_bf16(a0, b0, acc[0][0], 0, 0, 0);
      acc[0][1] = __builtin_amdgcn_mfma_f32_16x16x32_bf16(a0, b1, acc[0][1], 0, 0, 0);
      acc[1][0] = __builtin_amdgcn_mfma_f32_16x16x32_bf16(a1, b0, acc[1][0], 0, 0, 0);
      acc[1][1] = __builtin_amdgcn_mfma_f32_16x16x32_bf16(a1, b1, acc[1][1], 0, 0, 0);
    }
  }

#pragma unroll
  for (int sm = 0; sm < 2; ++sm)
#pragma unroll
    for (int sn = 0; sn < 2; ++sn)
#pragma unroll
      for (int r = 0; r < 4; ++r) {
        int row = m0 + wm + sm * 16 + quad * 4 + r;
        int col = n0 + wn + sn * 16 + l16;
        float val = acc[sm][sn][r] + bias[col];
        if (EPI == 1) {
          float msk = (seqs[row] != 0) ? 1.f : 0.f;
          Cf[(size_t)row * N + col] = (Cf[(size_t)row * N + col] + val) * msk;
        } else {
          Ch[(size_t)row * N + col] = __float2bfloat16(val);
        }
      }
}

// Fused: depthwise conv(k=3,pad1)+bias+silu -> y=D*xc -> LN_E -> v = yln*silu(z).
// (Scan term s is constant over e and cancels in the LN mean — dead code, removed.)
__global__ void conv_gate_kernel(const __hip_bfloat16* __restrict__ xzb,
                                 const float* __restrict__ cw, const float* __restrict__ cb,
                                 const float* __restrict__ D, const float* __restrict__ g,
                                 const float* __restrict__ bb,
                                 __hip_bfloat16* __restrict__ vb) {
  __shared__ float red[4];
  int r = blockIdx.x;   // b*L + l
  int e = threadIdx.x;  // 256
  int l = r % L_;
  float w0 = cw[e * 3 + 0], w1 = cw[e * 3 + 1], w2 = cw[e * 3 + 2];
  float xm1 = (l > 0)      ? __bfloat162float(xzb[(size_t)(r - 1) * 512 + e]) : 0.f;
  float x0  =                __bfloat162float(xzb[(size_t)r * 512 + e]);
  float xp1 = (l < L_ - 1) ? __bfloat162float(xzb[(size_t)(r + 1) * 512 + e]) : 0.f;
  float cv = w0 * xm1 + w1 * x0 + w2 * xp1 + cb[e];
  float sv = cv / (1.f + expf(-cv));  // silu
  float y = D[e] * sv;
  float mean = block_sum_256(y, red) * (1.f / 256.f);
  float d = y - mean;
  float var = block_sum_256(d * d, red) * (1.f / 256.f);
  float yln = d * rsqrtf(var + 1e-5f) * g[e] + bb[e];
  float z = __bfloat162float(xzb[(size_t)r * 512 + 256 + e]);
  vb[(size_t)r * E_ + e] = __float2bfloat16(yln * (z / (1.f + expf(-z))));
}

// logits[b,k] = xf[b,:] . item_emb[item_idxs[b,k], :]   (kept fp32)
__global__ void logits_kernel(const float* __restrict__ xf, const int* __restrict__ idxs,
                              const float* __restrict__ emb, float* __restrict__ out) {
  int p = blockIdx.x;  // b*K + k
  int b = p / K_;
  int t = threadIdx.x;  // 64
  int id = idxs[p];
  float a = xf[b * H_ + t] * emb[(size_t)id * H_ + t] +
            xf[b * H_ + 64 + t] * emb[(size_t)id * H_ + 64 + t];
  a = wave_sum64(a);
  if (t == 0) out[p] = a;
}

extern "C" void kernel_launch(void* const* d_in, const int* in_sizes, int n_in,
                              void* d_out, int out_size, void* d_ws, size_t ws_size,
                              hipStream_t stream) {
  const int*   seqs   = (const int*)d_in[0];
  const int*   idxs   = (const int*)d_in[1];
  const float* emb    = (const float*)d_in[2];
  const float* pos    = (const float*)d_in[3];
  const float* blk_g  = (const float*)d_in[4];
  const float* blk_b  = (const float*)d_in[5];
  const float* in_w   = (const float*)d_in[6];
  const float* in_b   = (const float*)d_in[7];
  const float* conv_w = (const float*)d_in[8];
  const float* conv_b = (const float*)d_in[9];
  // d_in[10..12] (xproj_w, xproj_b, A_log) feed only the scan term, which
  // cancels in the inner LayerNorm — unused.
  const float* D_p    = (const float*)d_in[13];
  const float* out_w  = (const float*)d_in[14];
  const float* out_b  = (const float*)d_in[15];
  const float* ig     = (const float*)d_in[16];
  const float* ib     = (const float*)d_in[17];
  const float* fg     = (const float*)d_in[18];
  const float* fb     = (const float*)d_in[19];
  float* out = (float*)d_out;
  float* ws = (float*)d_ws;

  // workspace layout (float units), total ~7.48M floats (~29.9 MB)
  // R6 bug: vb was given 819200 floats but needs 12800*256 bf16 = 1638400
  // floats -> overflowed into wti/wto (weights clobbered). Fixed here.
  float*           x   = ws;                                    // [12800,128] fp32   [0, 1638400)
  __hip_bfloat16*  xzb = (__hip_bfloat16*)(ws + 1638400);       // [12800,512] bf16   [1638400, 4915200)
  __hip_bfloat16*  ub  = (__hip_bfloat16*)(ws + 4915200);       // [12800,128] bf16   [4915200, 5734400)
  __hip_bfloat16*  vb  = (__hip_bfloat16*)(ws + 5734400);       // [12800,256] bf16   [5734400, 7372800)
  __hip_bfloat16*  wti = (__hip_bfloat16*)(ws + 7372800);       // [2,512,128] bf16   [7372800, 7438336)
  __hip_bfloat16*  wto = (__hip_bfloat16*)(ws + 7438336);       // [2,128,256] bf16   [7438336, 7471104)
  float*           xf  = ws + 7471104;                          // [64,128] fp32      [7471104, 7479296)

  // weight prep: in_w [2][128][512] -> wti [2][512][128]; out_w [2][256][128] -> wto [2][128][256]
  wtrans_kernel<<<dim3(512 / 64, 128 / 64, 2), 256, 0, stream>>>(in_w, wti, 128, 512);
  wtrans_kernel<<<dim3(128 / 64, 256 / 64, 2), 256, 0, stream>>>(out_w, wto, 256, 128);

  embed_kernel<<<NROW, 128, 0, stream>>>(seqs, emb, pos, x);

  for (int blk = 0; blk < 2; ++blk) {
    ln_h_kernel<<<NROW, 64, 0, stream>>>(x, blk_g + blk * H_, blk_b + blk * H_, ub);
    gemm_bf16_kernel<0><<<dim3(512 / 64, NROW / 64), 256, 0, stream>>>(
        ub, wti + (size_t)blk * 512 * 128, in_b + blk * 512, nullptr, xzb,
        NROW, 512, 128, nullptr);
    conv_gate_kernel<<<NROW, 256, 0, stream>>>(xzb, conv_w + blk * E_ * 3, conv_b + blk * E_,
                                               D_p + blk * E_, ig + blk * E_, ib + blk * E_, vb);
    gemm_bf16_kernel<1><<<dim3(128 / 64, NROW / 64), 256, 0, stream>>>(
        vb, wto + (size_t)blk * 128 * 256, out_b + blk * H_, x, nullptr,
        NROW, 128, 256, seqs);
  }

  ln_final_kernel<<<B_, 64, 0, stream>>>(x, fg, fb, xf);
  logits_kernel<<<B_ * K_, 64, 0, stream>>>(xf, idxs, emb, out);
}

// Round 8
// 203.819 us; speedup vs baseline: 3.7419x; 1.1015x over previous
//
#include <hip/hip_runtime.h>
#include <hip/hip_bf16.h>
#include <cmath>

#define B_ 64
#define L_ 200
#define H_ 128
#define E_ 256
#define K_ 101
#define NROW (B_ * L_)
#define CHUNK 50

using short8  = __attribute__((ext_vector_type(8))) short;
using short4_t = __attribute__((ext_vector_type(4))) short;
using f32x4   = __attribute__((ext_vector_type(4))) float;

__device__ __forceinline__ float wave_sum64(float v) {
#pragma unroll
  for (int o = 32; o > 0; o >>= 1) v += __shfl_xor(v, o, 64);
  return v;
}

__device__ __forceinline__ float bf2f(short s) {
  return __uint_as_float(((unsigned)(unsigned short)s) << 16);
}
__device__ __forceinline__ short f2bf(float f) {
  __hip_bfloat16 h = __float2bfloat16(f);
  return *reinterpret_cast<short*>(&h);
}

// x[b,l,h] = (item_emb[seq] + pos_emb[l]) * mask
__global__ void embed_kernel(const int* __restrict__ seqs, const float* __restrict__ emb,
                             const float* __restrict__ pos, float* __restrict__ x) {
  int r = blockIdx.x;          // b*L + l
  int h = threadIdx.x;         // 128
  int l = r % L_;
  int idx = seqs[r];
  float val = (idx != 0) ? (emb[(size_t)idx * H_ + h] + pos[l * H_ + h]) : 0.f;
  x[(size_t)r * H_ + h] = val;
}

// Final LN only at l = L-1, write xf[b,H] (fp32)
__global__ void ln_final_kernel(const float* __restrict__ x, const float* __restrict__ g,
                                const float* __restrict__ b, float* __restrict__ xf) {
  int bb = blockIdx.x;
  int t = threadIdx.x;  // 64
  size_t r = (size_t)bb * L_ + (L_ - 1);
  float v0 = x[r * H_ + t];
  float v1 = x[r * H_ + 64 + t];
  float mean = wave_sum64(v0 + v1) * (1.f / 128.f);
  float d0 = v0 - mean, d1 = v1 - mean;
  float var = wave_sum64(d0 * d0 + d1 * d1) * (1.f / 128.f);
  float rs = rsqrtf(var + 1e-5f);
  xf[bb * H_ + t]      = d0 * rs * g[t] + b[t];
  xf[bb * H_ + 64 + t] = d1 * rs * g[64 + t] + b[64 + t];
}

// Weight transpose + bf16 cast: W fp32 [K][N] -> Wt bf16 [N][K]; blockIdx.z = blk.
__global__ void wtrans_kernel(const float* __restrict__ W, __hip_bfloat16* __restrict__ Wt,
                              int K, int N) {
  __shared__ float ts[64][65];
  const float* Wb = W + (size_t)blockIdx.z * K * N;
  __hip_bfloat16* Wtb = Wt + (size_t)blockIdx.z * K * N;
  int n0 = blockIdx.x * 64, k0 = blockIdx.y * 64;
  int c = threadIdx.x & 63, r4 = threadIdx.x >> 6;
#pragma unroll
  for (int i = 0; i < 16; ++i) {
    int row = r4 * 16 + i;
    ts[row][c] = Wb[(size_t)(k0 + row) * N + n0 + c];
  }
  __syncthreads();
#pragma unroll
  for (int i = 0; i < 16; ++i) {
    int nrow = r4 * 16 + i;
    Wtb[(size_t)(n0 + nrow) * K + k0 + c] = __float2bfloat16(ts[c][nrow]);
  }
}

// One fused mamba block: LN_H -> in_proj MFMA -> conv+silu+LN_E+gate -> out_proj
// MFMA -> residual+mask.  One workgroup per (batch, 50-row L-chunk); all
// intermediates live in LDS.  Scan term cancels in LN_E (removed, see R6/R7).
// x is ping-ponged (xin -> xout) to avoid the halo in-place race.
__global__ __launch_bounds__(256, 1) void mamba_fused_kernel(
    const float* __restrict__ xin, float* __restrict__ xout,
    const __hip_bfloat16* __restrict__ wti,  // [512][128] bf16
    const __hip_bfloat16* __restrict__ wto,  // [128][256] bf16
    const float* __restrict__ lng, const float* __restrict__ lnb,  // [128]
    const float* __restrict__ in_b,                                // [512]
    const float* __restrict__ cw, const float* __restrict__ cb,    // conv
    const float* __restrict__ D_p, const float* __restrict__ ig,
    const float* __restrict__ ib, const float* __restrict__ out_b, // [128]
    const int* __restrict__ seqs) {
  __shared__ __align__(16) short u_s[64][136];   // LN output, rows = l0-1+i
  __shared__ __align__(16) short xz_s[64][520];  // in_proj output
  __shared__ __align__(16) short v_s[64][264];   // gate output

  const int bidx = blockIdx.x;
  const int b = bidx >> 2, c = bidx & 3;
  const int l0 = c * CHUNK;
  const int tid = threadIdx.x, wid = tid >> 6, lane = tid & 63;
  const int quad = lane >> 4, l16 = lane & 15;
  const int wm = (wid >> 1) * 32, wn = (wid & 1) * 32;
  const short* wtig = (const short*)wti;
  const short* wtog = (const short*)wto;

  // ---- Phase 1: LN_H rows l0-1..l0+50 -> u_s; rows >=52 zero. 2-row ILP. ----
  {
    float g0 = lng[lane * 2], g1 = lng[lane * 2 + 1];
    float q0 = lnb[lane * 2], q1 = lnb[lane * 2 + 1];
#pragma unroll
    for (int j = 0; j < 8; ++j) {
      int iA = wid * 16 + j, iB = iA + 8;
      int lA = l0 - 1 + iA, lB = l0 - 1 + iB;
      int lAr = min(max(lA, 0), L_ - 1), lBr = min(max(lB, 0), L_ - 1);
      bool vA = (iA < 52) && (lA >= 0) && (lA < L_);
      bool vB = (iB < 52) && (lB >= 0) && (lB < L_);
      float2 xa = *(const float2*)&xin[((size_t)b * L_ + lAr) * H_ + lane * 2];
      float2 xb = *(const float2*)&xin[((size_t)b * L_ + lBr) * H_ + lane * 2];
      float mA = wave_sum64(xa.x + xa.y) * (1.f / 128.f);
      float mB = wave_sum64(xb.x + xb.y) * (1.f / 128.f);
      float dA0 = xa.x - mA, dA1 = xa.y - mA;
      float dB0 = xb.x - mB, dB1 = xb.y - mB;
      float vrA = wave_sum64(dA0 * dA0 + dA1 * dA1) * (1.f / 128.f);
      float vrB = wave_sum64(dB0 * dB0 + dB1 * dB1) * (1.f / 128.f);
      float rA = rsqrtf(vrA + 1e-5f), rB = rsqrtf(vrB + 1e-5f);
      unsigned pA = 0, pB = 0;
      if (vA) {
        pA = ((unsigned)(unsigned short)f2bf(dA1 * rA * g1 + q1) << 16) |
             (unsigned short)f2bf(dA0 * rA * g0 + q0);
      }
      if (vB) {
        pB = ((unsigned)(unsigned short)f2bf(dB1 * rB * g1 + q1) << 16) |
             (unsigned short)f2bf(dB0 * rB * g0 + q0);
      }
      *(unsigned*)&u_s[iA][lane * 2] = pA;
      *(unsigned*)&u_s[iB][lane * 2] = pB;
    }
  }
  __syncthreads();

  // ---- Phase 2: xz = u @ wti^T + in_b  (M=64, N=512, K=128) -> xz_s bf16 ----
  {
    short8 afr[2][4];
#pragma unroll
    for (int sm = 0; sm < 2; ++sm)
#pragma unroll
      for (int kb = 0; kb < 4; ++kb)
        afr[sm][kb] = *(const short8*)&u_s[wm + sm * 16 + l16][kb * 32 + quad * 8];

    for (int n0 = 0; n0 < 512; n0 += 64) {
      f32x4 acc[2][2] = {{{0.f, 0.f, 0.f, 0.f}, {0.f, 0.f, 0.f, 0.f}},
                         {{0.f, 0.f, 0.f, 0.f}, {0.f, 0.f, 0.f, 0.f}}};
      short8 bfr[2][4];
#pragma unroll
      for (int sn = 0; sn < 2; ++sn)
#pragma unroll
        for (int kb = 0; kb < 4; ++kb)
          bfr[sn][kb] = *(const short8*)&wtig[(size_t)(n0 + wn + sn * 16 + l16) * 128 +
                                              kb * 32 + quad * 8];
#pragma unroll
      for (int kb = 0; kb < 4; ++kb) {
        acc[0][0] = __builtin_amdgcn_mfma_f32_16x16x32_bf16(afr[0][kb], bfr[0][kb], acc[0][0], 0, 0, 0);
        acc[0][1] = __builtin_amdgcn_mfma_f32_16x16x32_bf16(afr[0][kb], bfr[1][kb], acc[0][1], 0, 0, 0);
        acc[1][0] = __builtin_amdgcn_mfma_f32_16x16x32_bf16(afr[1][kb], bfr[0][kb], acc[1][0], 0, 0, 0);
        acc[1][1] = __builtin_amdgcn_mfma_f32_16x16x32_bf16(afr[1][kb], bfr[1][kb], acc[1][1], 0, 0, 0);
      }
#pragma unroll
      for (int sm = 0; sm < 2; ++sm)
#pragma unroll
        for (int sn = 0; sn < 2; ++sn) {
          int col = n0 + wn + sn * 16 + l16;
          float bz = in_b[col];
#pragma unroll
          for (int r = 0; r < 4; ++r) {
            int row = wm + sm * 16 + quad * 4 + r;
            xz_s[row][col] = f2bf(acc[sm][sn][r] + bz);
          }
        }
    }
  }
  __syncthreads();

  // ---- Phase 3: conv+silu -> y=D*xc -> LN_E -> v = yln*silu(z) -> v_s ----
  {
    const int e0 = lane * 4;
    float w0[4], w1[4], w2[4], cbv[4], Dv[4], gv[4], bv[4];
#pragma unroll
    for (int j = 0; j < 4; ++j) {
      w0[j] = cw[(e0 + j) * 3 + 0];
      w1[j] = cw[(e0 + j) * 3 + 1];
      w2[j] = cw[(e0 + j) * 3 + 2];
      cbv[j] = cb[e0 + j]; Dv[j] = D_p[e0 + j];
      gv[j] = ig[e0 + j];  bv[j] = ib[e0 + j];
    }
#pragma unroll
    for (int i = wid * 16; i < wid * 16 + 16; ++i) {
      int ir = min(i, CHUNK - 1);           // clamp for safe LDS reads
      int l = l0 + ir;
      bool hasL = (l - 1 >= 0), hasR = (l + 1 <= L_ - 1);
      short4_t sm1 = *(const short4_t*)&xz_s[ir][e0];
      short4_t s0  = *(const short4_t*)&xz_s[ir + 1][e0];
      short4_t sp1 = *(const short4_t*)&xz_s[ir + 2][e0];
      short4_t sz  = *(const short4_t*)&xz_s[ir + 1][256 + e0];
      float y[4], part = 0.f;
#pragma unroll
      for (int j = 0; j < 4; ++j) {
        float xm1 = hasL ? bf2f(sm1[j]) : 0.f;
        float x0  = bf2f(s0[j]);
        float xp1 = hasR ? bf2f(sp1[j]) : 0.f;
        float cv = w0[j] * xm1 + w1[j] * x0 + w2[j] * xp1 + cbv[j];
        float sv = cv / (1.f + __expf(-cv));
        y[j] = Dv[j] * sv;
        part += y[j];
      }
      float mean = wave_sum64(part) * (1.f / 256.f);
      float vp = 0.f;
#pragma unroll
      for (int j = 0; j < 4; ++j) { y[j] -= mean; vp += y[j] * y[j]; }
      float rs = rsqrtf(wave_sum64(vp) * (1.f / 256.f) + 1e-5f);
      short4_t outv;
#pragma unroll
      for (int j = 0; j < 4; ++j) {
        float yln = y[j] * rs * gv[j] + bv[j];
        float z = bf2f(sz[j]);
        outv[j] = f2bf(yln * (z / (1.f + __expf(-z))));
      }
      if (i >= CHUNK) outv = short4_t{0, 0, 0, 0};
      *(short4_t*)&v_s[i][e0] = outv;
    }
  }
  __syncthreads();

  // ---- Phase 4: out = v @ wto^T + out_b; x' = (x + out)*mask (rows<50) ----
  for (int n0 = 0; n0 < 128; n0 += 64) {
    f32x4 acc[2][2] = {{{0.f, 0.f, 0.f, 0.f}, {0.f, 0.f, 0.f, 0.f}},
                       {{0.f, 0.f, 0.f, 0.f}, {0.f, 0.f, 0.f, 0.f}}};
#pragma unroll
    for (int kb = 0; kb < 8; ++kb) {
      short8 a0 = *(const short8*)&v_s[wm + l16][kb * 32 + quad * 8];
      short8 a1 = *(const short8*)&v_s[wm + 16 + l16][kb * 32 + quad * 8];
      short8 b0 = *(const short8*)&wtog[(size_t)(n0 + wn + l16) * 256 + kb * 32 + quad * 8];
      short8 b1 = *(const short8*)&wtog[(size_t)(n0 + wn + 16 + l16) * 256 + kb * 32 + quad * 8];
      acc[0][0] = __builtin_amdgcn_mfma_f32_16x16x32_bf16(a0, b0, acc[0][0], 0, 0, 0);
      acc[0][1] = __builtin_amdgcn_mfma_f32_16x16x32_bf16(a0, b1, acc[0][1], 0, 0, 0);
      acc[1][0] = __builtin_amdgcn_mfma_f32_16x16x32_bf16(a1, b0, acc[1][0], 0, 0, 0);
      acc[1][1] = __builtin_amdgcn_mfma_f32_16x16x32_bf16(a1, b1, acc[1][1], 0, 0, 0);
    }
#pragma unroll
    for (int sm = 0; sm < 2; ++sm)
#pragma unroll
      for (int sn = 0; sn < 2; ++sn)
#pragma unroll
        for (int r = 0; r < 4; ++r) {
          int row = wm + sm * 16 + quad * 4 + r;
          if (row < CHUNK) {
            int l = l0 + row;
            int col = n0 + wn + sn * 16 + l16;
            size_t gi = ((size_t)b * L_ + l) * H_ + col;
            float val = acc[sm][sn][r] + out_b[col];
            float msk = (seqs[b * L_ + l] != 0) ? 1.f : 0.f;
            xout[gi] = (xin[gi] + val) * msk;
          }
        }
  }
}

// logits[b,k] = xf[b,:] . item_emb[item_idxs[b,k], :]   (fp32)
__global__ void logits_kernel(const float* __restrict__ xf, const int* __restrict__ idxs,
                              const float* __restrict__ emb, float* __restrict__ out) {
  int p = blockIdx.x;  // b*K + k
  int b = p / K_;
  int t = threadIdx.x;  // 64
  int id = idxs[p];
  float a = xf[b * H_ + t] * emb[(size_t)id * H_ + t] +
            xf[b * H_ + 64 + t] * emb[(size_t)id * H_ + 64 + t];
  a = wave_sum64(a);
  if (t == 0) out[p] = a;
}

extern "C" void kernel_launch(void* const* d_in, const int* in_sizes, int n_in,
                              void* d_out, int out_size, void* d_ws, size_t ws_size,
                              hipStream_t stream) {
  const int*   seqs   = (const int*)d_in[0];
  const int*   idxs   = (const int*)d_in[1];
  const float* emb    = (const float*)d_in[2];
  const float* pos    = (const float*)d_in[3];
  const float* blk_g  = (const float*)d_in[4];
  const float* blk_b  = (const float*)d_in[5];
  const float* in_w   = (const float*)d_in[6];
  const float* in_b   = (const float*)d_in[7];
  const float* conv_w = (const float*)d_in[8];
  const float* conv_b = (const float*)d_in[9];
  // d_in[10..12] (xproj_w, xproj_b, A_log) feed only the scan term, which
  // cancels in the inner LayerNorm — unused.
  const float* D_p    = (const float*)d_in[13];
  const float* out_w  = (const float*)d_in[14];
  const float* out_b  = (const float*)d_in[15];
  const float* ig     = (const float*)d_in[16];
  const float* ib     = (const float*)d_in[17];
  const float* fg     = (const float*)d_in[18];
  const float* fb     = (const float*)d_in[19];
  float* out = (float*)d_out;
  float* ws = (float*)d_ws;

  // workspace (float units): x, x2 ping-pong; weights; xf. ~13.5 MB
  float*           x   = ws;                                 // [12800,128]
  float*           x2  = ws + 1638400;                       // [12800,128]
  __hip_bfloat16*  wti = (__hip_bfloat16*)(ws + 3276800);    // [2,512,128] bf16
  __hip_bfloat16*  wto = (__hip_bfloat16*)(ws + 3342336);    // [2,128,256] bf16
  float*           xf  = ws + 3375104;                       // [64,128]

  wtrans_kernel<<<dim3(512 / 64, 128 / 64, 2), 256, 0, stream>>>(in_w, wti, 128, 512);
  wtrans_kernel<<<dim3(128 / 64, 256 / 64, 2), 256, 0, stream>>>(out_w, wto, 256, 128);

  embed_kernel<<<NROW, 128, 0, stream>>>(seqs, emb, pos, x);

  for (int blk = 0; blk < 2; ++blk) {
    const float* xi = (blk == 0) ? x : x2;
    float*       xo = (blk == 0) ? x2 : x;
    mamba_fused_kernel<<<B_ * 4, 256, 0, stream>>>(
        xi, xo,
        wti + (size_t)blk * 512 * 128, wto + (size_t)blk * 128 * 256,
        blk_g + blk * H_, blk_b + blk * H_, in_b + blk * 512,
        conv_w + blk * E_ * 3, conv_b + blk * E_,
        D_p + blk * E_, ig + blk * E_, ib + blk * E_,
        out_b + blk * H_, seqs);
  }

  ln_final_kernel<<<B_, 64, 0, stream>>>(x, fg, fb, xf);
  logits_kernel<<<B_ * K_, 64, 0, stream>>>(xf, idxs, emb, out);
}

// Round 9
// 197.145 us; speedup vs baseline: 3.8686x; 1.0339x over previous
//
#include <hip/hip_runtime.h>
#include <hip/hip_bf16.h>
#include <cmath>

#define B_ 64
#define L_ 200
#define H_ 128
#define E_ 256
#define K_ 101
#define NROW (B_ * L_)
#define CHUNK 30
#define NCH 7  // ceil(200/30)

using short8   = __attribute__((ext_vector_type(8))) short;
using short4_t = __attribute__((ext_vector_type(4))) short;
using f32x4    = __attribute__((ext_vector_type(4))) float;

__device__ __forceinline__ float wave_sum64(float v) {
#pragma unroll
  for (int o = 32; o > 0; o >>= 1) v += __shfl_xor(v, o, 64);
  return v;
}

__device__ __forceinline__ float bf2f(short s) {
  return __uint_as_float(((unsigned)(unsigned short)s) << 16);
}
__device__ __forceinline__ short f2bf(float f) {
  __hip_bfloat16 h = __float2bfloat16(f);
  return *reinterpret_cast<short*>(&h);
}

// x[b,l,h] = (item_emb[seq] + pos_emb[l]) * mask
__global__ void embed_kernel(const int* __restrict__ seqs, const float* __restrict__ emb,
                             const float* __restrict__ pos, float* __restrict__ x) {
  int r = blockIdx.x;          // b*L + l
  int h = threadIdx.x;         // 128
  int l = r % L_;
  int idx = seqs[r];
  float val = (idx != 0) ? (emb[(size_t)idx * H_ + h] + pos[l * H_ + h]) : 0.f;
  x[(size_t)r * H_ + h] = val;
}

// Weight transpose + bf16 cast: W fp32 [K][N] -> Wt bf16 [N][K]; blockIdx.z = blk.
__global__ void wtrans_kernel(const float* __restrict__ W, __hip_bfloat16* __restrict__ Wt,
                              int K, int N) {
  __shared__ float ts[64][65];
  const float* Wb = W + (size_t)blockIdx.z * K * N;
  __hip_bfloat16* Wtb = Wt + (size_t)blockIdx.z * K * N;
  int n0 = blockIdx.x * 64, k0 = blockIdx.y * 64;
  int c = threadIdx.x & 63, r4 = threadIdx.x >> 6;
#pragma unroll
  for (int i = 0; i < 16; ++i) {
    int row = r4 * 16 + i;
    ts[row][c] = Wb[(size_t)(k0 + row) * N + n0 + c];
  }
  __syncthreads();
#pragma unroll
  for (int i = 0; i < 16; ++i) {
    int nrow = r4 * 16 + i;
    Wtb[(size_t)(n0 + nrow) * K + k0 + c] = __float2bfloat16(ts[c][nrow]);
  }
}

// Fused mamba block, v2 (occupancy-first): CHUNK=30, M=32 tiles, 43 KB LDS
// -> 3 blocks/CU.  Gate output v[m] overwrites the z-half of xz_s row m+1
// (z row k is read only by the same wave-row computation that overwrites it;
// in-order DS pipe makes read-before-write safe). Scan term cancels in LN_E
// (removed; see R6).  x ping-ponged xin->xout for the halo.
__global__ __launch_bounds__(256, 3) void mamba_fused_kernel(
    const float* __restrict__ xin, float* __restrict__ xout,
    const __hip_bfloat16* __restrict__ wti,  // [512][128] bf16
    const __hip_bfloat16* __restrict__ wto,  // [128][256] bf16
    const float* __restrict__ lng, const float* __restrict__ lnb,  // [128]
    const float* __restrict__ in_b,                                // [512]
    const float* __restrict__ cw, const float* __restrict__ cb,    // conv
    const float* __restrict__ D_p, const float* __restrict__ ig,
    const float* __restrict__ ib, const float* __restrict__ out_b, // [128]
    const int* __restrict__ seqs) {
  __shared__ __align__(16) short u_s[32][136];   // LN out; row i <-> l = l0-1+i
  __shared__ __align__(16) short xz_s[33][520];  // in_proj out; z-half becomes v

  const int bidx = blockIdx.x;
  const int b = bidx / NCH, c = bidx % NCH;
  const int l0 = c * CHUNK;
  const int tid = threadIdx.x, wid = tid >> 6, lane = tid & 63;
  const int quad = lane >> 4, l16 = lane & 15;
  const int wm = (wid >> 1) * 16;   // m-tile: rows wm..wm+15
  const int wn = (wid & 1) * 32;    // n-subtile within each 64-col group
  const short* wtig = (const short*)wti;
  const short* wtog = (const short*)wto;

  // ---- Phase 1: LN_H rows i=0..31 (l = l0-1+i) -> u_s bf16; OOB rows zero ----
  {
    float g0 = lng[lane * 2], g1 = lng[lane * 2 + 1];
    float q0 = lnb[lane * 2], q1 = lnb[lane * 2 + 1];
#pragma unroll
    for (int j = 0; j < 4; ++j) {
      int iA = wid * 8 + j, iB = iA + 4;
      int lA = l0 - 1 + iA, lB = l0 - 1 + iB;
      int lAr = min(max(lA, 0), L_ - 1), lBr = min(max(lB, 0), L_ - 1);
      bool vA = (lA >= 0) && (lA < L_);
      bool vB = (lB >= 0) && (lB < L_);
      float2 xa = *(const float2*)&xin[((size_t)b * L_ + lAr) * H_ + lane * 2];
      float2 xb = *(const float2*)&xin[((size_t)b * L_ + lBr) * H_ + lane * 2];
      float mA = wave_sum64(xa.x + xa.y) * (1.f / 128.f);
      float mB = wave_sum64(xb.x + xb.y) * (1.f / 128.f);
      float dA0 = xa.x - mA, dA1 = xa.y - mA;
      float dB0 = xb.x - mB, dB1 = xb.y - mB;
      float vrA = wave_sum64(dA0 * dA0 + dA1 * dA1) * (1.f / 128.f);
      float vrB = wave_sum64(dB0 * dB0 + dB1 * dB1) * (1.f / 128.f);
      float rA = rsqrtf(vrA + 1e-5f), rB = rsqrtf(vrB + 1e-5f);
      unsigned pA = 0, pB = 0;
      if (vA) {
        pA = ((unsigned)(unsigned short)f2bf(dA1 * rA * g1 + q1) << 16) |
             (unsigned short)f2bf(dA0 * rA * g0 + q0);
      }
      if (vB) {
        pB = ((unsigned)(unsigned short)f2bf(dB1 * rB * g1 + q1) << 16) |
             (unsigned short)f2bf(dB0 * rB * g0 + q0);
      }
      *(unsigned*)&u_s[iA][lane * 2] = pA;
      *(unsigned*)&u_s[iB][lane * 2] = pB;
    }
  }
  __syncthreads();

  // ---- Phase 2: xz = u @ wti^T + in_b  (M=32, N=512, K=128) -> xz_s bf16 ----
  {
    short8 afr[4];
#pragma unroll
    for (int kb = 0; kb < 4; ++kb)
      afr[kb] = *(const short8*)&u_s[wm + l16][kb * 32 + quad * 8];

    short8 bbuf[2][2][4];  // [buf][sn][kb], double-buffered across n-groups
#pragma unroll
    for (int sn = 0; sn < 2; ++sn)
#pragma unroll
      for (int kb = 0; kb < 4; ++kb)
        bbuf[0][sn][kb] = *(const short8*)&wtig[(size_t)(wn + sn * 16 + l16) * 128 +
                                                kb * 32 + quad * 8];
    for (int g = 0; g < 8; ++g) {
      int cur = g & 1;
      if (g < 7) {
        int n1 = (g + 1) * 64;
#pragma unroll
        for (int sn = 0; sn < 2; ++sn)
#pragma unroll
          for (int kb = 0; kb < 4; ++kb)
            bbuf[cur ^ 1][sn][kb] =
                *(const short8*)&wtig[(size_t)(n1 + wn + sn * 16 + l16) * 128 +
                                      kb * 32 + quad * 8];
      }
      f32x4 acc0 = {0.f, 0.f, 0.f, 0.f}, acc1 = {0.f, 0.f, 0.f, 0.f};
#pragma unroll
      for (int kb = 0; kb < 4; ++kb) {
        acc0 = __builtin_amdgcn_mfma_f32_16x16x32_bf16(afr[kb], bbuf[cur][0][kb], acc0, 0, 0, 0);
        acc1 = __builtin_amdgcn_mfma_f32_16x16x32_bf16(afr[kb], bbuf[cur][1][kb], acc1, 0, 0, 0);
      }
      int col0 = g * 64 + wn + l16;
      float bz0 = in_b[col0], bz1 = in_b[col0 + 16];
#pragma unroll
      for (int r = 0; r < 4; ++r) {
        int row = wm + quad * 4 + r;
        xz_s[row][col0]      = f2bf(acc0[r] + bz0);
        xz_s[row][col0 + 16] = f2bf(acc1[r] + bz1);
      }
    }
  }
  __syncthreads();

  // ---- Phase 3: conv+silu -> y=D*xc -> LN_E -> v = yln*silu(z); v overwrites
  //      z-half of row m+1 (same-thread read-before-write). Rows m>=real -> 0.
  {
    const int e0 = lane * 4;
    float w0[4], w1[4], w2[4], cbv[4], Dv[4], gv[4], bv[4];
#pragma unroll
    for (int j = 0; j < 4; ++j) {
      w0[j] = cw[(e0 + j) * 3 + 0];
      w1[j] = cw[(e0 + j) * 3 + 1];
      w2[j] = cw[(e0 + j) * 3 + 2];
      cbv[j] = cb[e0 + j]; Dv[j] = D_p[e0 + j];
      gv[j] = ig[e0 + j];  bv[j] = ib[e0 + j];
    }
    for (int j = 0; j < 8; ++j) {
      int m = wid * 8 + j;
      int l = l0 + m;
      int mr = min(m, CHUNK - 1);  // clamp reads to rows <= 31
      int lr = l0 + mr;
      bool hasL = (lr >= 1), hasR = (lr + 1 < L_);
      short4_t sm1 = *(const short4_t*)&xz_s[mr][e0];
      short4_t s0  = *(const short4_t*)&xz_s[mr + 1][e0];
      short4_t sp1 = *(const short4_t*)&xz_s[mr + 2][e0];
      short4_t sz  = *(const short4_t*)&xz_s[mr + 1][256 + e0];
      float y[4], part = 0.f;
#pragma unroll
      for (int jj = 0; jj < 4; ++jj) {
        float xm1 = hasL ? bf2f(sm1[jj]) : 0.f;
        float x0  = bf2f(s0[jj]);
        float xp1 = hasR ? bf2f(sp1[jj]) : 0.f;
        float cv = w0[jj] * xm1 + w1[jj] * x0 + w2[jj] * xp1 + cbv[jj];
        float sv = cv / (1.f + __expf(-cv));
        y[jj] = Dv[jj] * sv;
        part += y[jj];
      }
      float mean = wave_sum64(part) * (1.f / 256.f);
      float vp = 0.f;
#pragma unroll
      for (int jj = 0; jj < 4; ++jj) { y[jj] -= mean; vp += y[jj] * y[jj]; }
      float rs = rsqrtf(wave_sum64(vp) * (1.f / 256.f) + 1e-5f);
      short4_t outv;
#pragma unroll
      for (int jj = 0; jj < 4; ++jj) {
        float yln = y[jj] * rs * gv[jj] + bv[jj];
        float z = bf2f(sz[jj]);
        outv[jj] = f2bf(yln * (z / (1.f + __expf(-z))));
      }
      if (m >= CHUNK || l >= L_) outv = short4_t{0, 0, 0, 0};
      *(short4_t*)&xz_s[m + 1][256 + e0] = outv;  // v[m] -> z-half row m+1
    }
  }
  __syncthreads();

  // ---- Phase 4: out = v @ wto^T + out_b; x' = (x + out)*mask ----
  {
    short8 vfr[8];
#pragma unroll
    for (int kb = 0; kb < 8; ++kb)
      vfr[kb] = *(const short8*)&xz_s[wm + l16 + 1][256 + kb * 32 + quad * 8];
    for (int g = 0; g < 2; ++g) {
      int n0 = g * 64;
      f32x4 acc0 = {0.f, 0.f, 0.f, 0.f}, acc1 = {0.f, 0.f, 0.f, 0.f};
#pragma unroll
      for (int kb = 0; kb < 8; ++kb) {
        short8 b0 = *(const short8*)&wtog[(size_t)(n0 + wn + l16) * 256 + kb * 32 + quad * 8];
        short8 b1 = *(const short8*)&wtog[(size_t)(n0 + wn + 16 + l16) * 256 + kb * 32 + quad * 8];
        acc0 = __builtin_amdgcn_mfma_f32_16x16x32_bf16(vfr[kb], b0, acc0, 0, 0, 0);
        acc1 = __builtin_amdgcn_mfma_f32_16x16x32_bf16(vfr[kb], b1, acc1, 0, 0, 0);
      }
#pragma unroll
      for (int r = 0; r < 4; ++r) {
        int m = wm + quad * 4 + r;
        int l = l0 + m;
        if (m < CHUNK && l < L_) {
          int col0 = n0 + wn + l16;
          size_t gi = ((size_t)b * L_ + l) * H_;
          float msk = (seqs[b * L_ + l] != 0) ? 1.f : 0.f;
          xout[gi + col0]      = (xin[gi + col0] + acc0[r] + out_b[col0]) * msk;
          xout[gi + col0 + 16] = (xin[gi + col0 + 16] + acc1[r] + out_b[col0 + 16]) * msk;
        }
      }
    }
  }
}

// Fused final-LN + logits: each block p=(b,k) recomputes LN of x[b,L-1] (cheap,
// one wave) and dots with item_emb[idxs[p]].
__global__ void logits_kernel(const float* __restrict__ x, const float* __restrict__ fg,
                              const float* __restrict__ fb, const int* __restrict__ idxs,
                              const float* __restrict__ emb, float* __restrict__ out) {
  int p = blockIdx.x;  // b*K + k
  int b = p / K_;
  int t = threadIdx.x;  // 64
  size_t r = (size_t)b * L_ + (L_ - 1);
  float v0 = x[r * H_ + t];
  float v1 = x[r * H_ + 64 + t];
  float mean = wave_sum64(v0 + v1) * (1.f / 128.f);
  float d0 = v0 - mean, d1 = v1 - mean;
  float var = wave_sum64(d0 * d0 + d1 * d1) * (1.f / 128.f);
  float rs = rsqrtf(var + 1e-5f);
  float xf0 = d0 * rs * fg[t] + fb[t];
  float xf1 = d1 * rs * fg[64 + t] + fb[64 + t];
  int id = idxs[p];
  float a = xf0 * emb[(size_t)id * H_ + t] + xf1 * emb[(size_t)id * H_ + 64 + t];
  a = wave_sum64(a);
  if (t == 0) out[p] = a;
}

extern "C" void kernel_launch(void* const* d_in, const int* in_sizes, int n_in,
                              void* d_out, int out_size, void* d_ws, size_t ws_size,
                              hipStream_t stream) {
  const int*   seqs   = (const int*)d_in[0];
  const int*   idxs   = (const int*)d_in[1];
  const float* emb    = (const float*)d_in[2];
  const float* pos    = (const float*)d_in[3];
  const float* blk_g  = (const float*)d_in[4];
  const float* blk_b  = (const float*)d_in[5];
  const float* in_w   = (const float*)d_in[6];
  const float* in_b   = (const float*)d_in[7];
  const float* conv_w = (const float*)d_in[8];
  const float* conv_b = (const float*)d_in[9];
  // d_in[10..12] (xproj_w, xproj_b, A_log) feed only the scan term, which
  // cancels in the inner LayerNorm — unused.
  const float* D_p    = (const float*)d_in[13];
  const float* out_w  = (const float*)d_in[14];
  const float* out_b  = (const float*)d_in[15];
  const float* ig     = (const float*)d_in[16];
  const float* ib     = (const float*)d_in[17];
  const float* fg     = (const float*)d_in[18];
  const float* fb     = (const float*)d_in[19];
  float* out = (float*)d_out;
  float* ws = (float*)d_ws;

  // workspace (float units): x, x2 ping-pong; bf16 weights. ~13.4 MB
  float*           x   = ws;                                 // [12800,128]
  float*           x2  = ws + 1638400;                       // [12800,128]
  __hip_bfloat16*  wti = (__hip_bfloat16*)(ws + 3276800);    // [2,512,128] bf16
  __hip_bfloat16*  wto = (__hip_bfloat16*)(ws + 3342336);    // [2,128,256] bf16

  wtrans_kernel<<<dim3(512 / 64, 128 / 64, 2), 256, 0, stream>>>(in_w, wti, 128, 512);
  wtrans_kernel<<<dim3(128 / 64, 256 / 64, 2), 256, 0, stream>>>(out_w, wto, 256, 128);

  embed_kernel<<<NROW, 128, 0, stream>>>(seqs, emb, pos, x);

  for (int blk = 0; blk < 2; ++blk) {
    const float* xi = (blk == 0) ? x : x2;
    float*       xo = (blk == 0) ? x2 : x;
    mamba_fused_kernel<<<B_ * NCH, 256, 0, stream>>>(
        xi, xo,
        wti + (size_t)blk * 512 * 128, wto + (size_t)blk * 128 * 256,
        blk_g + blk * H_, blk_b + blk * H_, in_b + blk * 512,
        conv_w + blk * E_ * 3, conv_b + blk * E_,
        D_p + blk * E_, ig + blk * E_, ib + blk * E_,
        out_b + blk * H_, seqs);
  }

  logits_kernel<<<B_ * K_, 64, 0, stream>>>(x, fg, fb, idxs, emb, out);
}

// Round 10
// 185.021 us; speedup vs baseline: 4.1221x; 1.0655x over previous
//
#include <hip/hip_runtime.h>
#include <hip/hip_bf16.h>
#include <cmath>

#define B_ 64
#define L_ 200
#define H_ 128
#define E_ 256
#define K_ 101
#define NROW (B_ * L_)
#define CHUNK 14
#define NCH 15  // ceil(200/14)

using short8   = __attribute__((ext_vector_type(8))) short;
using short4_t = __attribute__((ext_vector_type(4))) short;
using f32x4    = __attribute__((ext_vector_type(4))) float;

__device__ __forceinline__ float wave_sum64(float v) {
#pragma unroll
  for (int o = 32; o > 0; o >>= 1) v += __shfl_xor(v, o, 64);
  return v;
}

__device__ __forceinline__ float bf2f(short s) {
  return __uint_as_float(((unsigned)(unsigned short)s) << 16);
}
__device__ __forceinline__ short f2bf(float f) {
  __hip_bfloat16 h = __float2bfloat16(f);
  return *reinterpret_cast<short*>(&h);
}

// Combined weight transpose + bf16 cast for both weight tensors.
// blocks 0..31:  in_w  [2][128][512] -> wti [2][512][128]
// blocks 32..47: out_w [2][256][128] -> wto [2][128][256]
__global__ void wtrans_kernel(const float* __restrict__ in_w,
                              const float* __restrict__ out_w,
                              __hip_bfloat16* __restrict__ wti,
                              __hip_bfloat16* __restrict__ wto) {
  __shared__ float ts[64][65];
  int bx = blockIdx.x;
  const float* W; __hip_bfloat16* Wt; int K, N, n0, k0;
  if (bx < 32) {
    int blk = bx >> 4, t = bx & 15;
    K = 128; N = 512;
    W = in_w + (size_t)blk * K * N; Wt = wti + (size_t)blk * K * N;
    n0 = (t & 7) * 64; k0 = (t >> 3) * 64;
  } else {
    int b2 = bx - 32, blk = b2 >> 3, t = b2 & 7;
    K = 256; N = 128;
    W = out_w + (size_t)blk * K * N; Wt = wto + (size_t)blk * K * N;
    n0 = (t & 1) * 64; k0 = (t >> 1) * 64;
  }
  int c = threadIdx.x & 63, r4 = threadIdx.x >> 6;
#pragma unroll
  for (int i = 0; i < 16; ++i) {
    int row = r4 * 16 + i;
    ts[row][c] = W[(size_t)(k0 + row) * N + n0 + c];
  }
  __syncthreads();
#pragma unroll
  for (int i = 0; i < 16; ++i) {
    int nrow = r4 * 16 + i;
    Wt[(size_t)(n0 + nrow) * K + k0 + c] = __float2bfloat16(ts[c][nrow]);
  }
}

// Fused mamba block, v3 (grid-wide co-residency): CHUNK=14, M=16 tile,
// 22 KB LDS, 4 blocks/CU, 960 blocks -> all co-resident.
// EMBED=1: layer-0 input is computed on the fly from seqs/emb/pos (both in
// phase 1 and for the phase-4 residual) — embed kernel eliminated.
// Gate output v[m] overwrites the z-half of xz_s row m+1 (same-thread
// read-before-write, in-order DS pipe). Scan term cancels in LN_E (see R6).
template <int EMBED>
__global__ __launch_bounds__(256, 4) void mamba_fused_kernel(
    const float* __restrict__ xin, float* __restrict__ xout,
    const int* __restrict__ seqs, const float* __restrict__ emb,
    const float* __restrict__ pos,
    const __hip_bfloat16* __restrict__ wti,  // [512][128] bf16
    const __hip_bfloat16* __restrict__ wto,  // [128][256] bf16
    const float* __restrict__ lng, const float* __restrict__ lnb,  // [128]
    const float* __restrict__ in_b,                                // [512]
    const float* __restrict__ cw, const float* __restrict__ cb,    // conv
    const float* __restrict__ D_p, const float* __restrict__ ig,
    const float* __restrict__ ib, const float* __restrict__ out_b) {
  __shared__ __align__(16) short u_s[16][136];   // LN out; row i <-> l = l0-1+i
  __shared__ __align__(16) short xz_s[17][520];  // in_proj out; z-half becomes v

  const int bidx = blockIdx.x;
  const int b = bidx / NCH, c = bidx % NCH;
  const int l0 = c * CHUNK;
  const int tid = threadIdx.x, wid = tid >> 6, lane = tid & 63;
  const int quad = lane >> 4, l16 = lane & 15;
  const short* wtig = (const short*)wti;
  const short* wtog = (const short*)wto;

  // ---- Phase 1: LN_H rows i=0..15 (l = l0-1+i) -> u_s bf16; OOB rows zero ----
  {
    float g0 = lng[lane * 2], g1 = lng[lane * 2 + 1];
    float q0 = lnb[lane * 2], q1 = lnb[lane * 2 + 1];
#pragma unroll
    for (int j = 0; j < 2; ++j) {
      int iA = wid * 4 + j, iB = iA + 2;
      int lA = l0 - 1 + iA, lB = l0 - 1 + iB;
      int lAr = min(max(lA, 0), L_ - 1), lBr = min(max(lB, 0), L_ - 1);
      bool vA = (lA >= 0) && (lA < L_);
      bool vB = (lB >= 0) && (lB < L_);
      float2 xa, xb;
      if (EMBED) {
        int idA = seqs[b * L_ + lAr], idB = seqs[b * L_ + lBr];
        if (idA != 0) {
          float2 ea = *(const float2*)&emb[(size_t)idA * H_ + lane * 2];
          float2 pa = *(const float2*)&pos[(size_t)lAr * H_ + lane * 2];
          xa = make_float2(ea.x + pa.x, ea.y + pa.y);
        } else xa = make_float2(0.f, 0.f);
        if (idB != 0) {
          float2 eb = *(const float2*)&emb[(size_t)idB * H_ + lane * 2];
          float2 pb = *(const float2*)&pos[(size_t)lBr * H_ + lane * 2];
          xb = make_float2(eb.x + pb.x, eb.y + pb.y);
        } else xb = make_float2(0.f, 0.f);
      } else {
        xa = *(const float2*)&xin[((size_t)b * L_ + lAr) * H_ + lane * 2];
        xb = *(const float2*)&xin[((size_t)b * L_ + lBr) * H_ + lane * 2];
      }
      float mA = wave_sum64(xa.x + xa.y) * (1.f / 128.f);
      float mB = wave_sum64(xb.x + xb.y) * (1.f / 128.f);
      float dA0 = xa.x - mA, dA1 = xa.y - mA;
      float dB0 = xb.x - mB, dB1 = xb.y - mB;
      float vrA = wave_sum64(dA0 * dA0 + dA1 * dA1) * (1.f / 128.f);
      float vrB = wave_sum64(dB0 * dB0 + dB1 * dB1) * (1.f / 128.f);
      float rA = rsqrtf(vrA + 1e-5f), rB = rsqrtf(vrB + 1e-5f);
      unsigned pA = 0, pB = 0;
      if (vA) {
        pA = ((unsigned)(unsigned short)f2bf(dA1 * rA * g1 + q1) << 16) |
             (unsigned short)f2bf(dA0 * rA * g0 + q0);
      }
      if (vB) {
        pB = ((unsigned)(unsigned short)f2bf(dB1 * rB * g1 + q1) << 16) |
             (unsigned short)f2bf(dB0 * rB * g0 + q0);
      }
      *(unsigned*)&u_s[iA][lane * 2] = pA;
      *(unsigned*)&u_s[iB][lane * 2] = pB;
    }
  }
  __syncthreads();

  // ---- Phase 2: xz = u @ wti^T + in_b (M=16, N=512, K=128); wave w owns
  //      cols [w*128, w*128+128) ----
  {
    short8 afr[4];
#pragma unroll
    for (int kb = 0; kb < 4; ++kb)
      afr[kb] = *(const short8*)&u_s[l16][kb * 32 + quad * 8];
#pragma unroll
    for (int g = 0; g < 4; ++g) {
      int ncol = wid * 128 + g * 32;
      short8 bfr0[4], bfr1[4];
#pragma unroll
      for (int kb = 0; kb < 4; ++kb) {
        bfr0[kb] = *(const short8*)&wtig[(size_t)(ncol + l16) * 128 + kb * 32 + quad * 8];
        bfr1[kb] = *(const short8*)&wtig[(size_t)(ncol + 16 + l16) * 128 + kb * 32 + quad * 8];
      }
      f32x4 acc0 = {0.f, 0.f, 0.f, 0.f}, acc1 = {0.f, 0.f, 0.f, 0.f};
#pragma unroll
      for (int kb = 0; kb < 4; ++kb) {
        acc0 = __builtin_amdgcn_mfma_f32_16x16x32_bf16(afr[kb], bfr0[kb], acc0, 0, 0, 0);
        acc1 = __builtin_amdgcn_mfma_f32_16x16x32_bf16(afr[kb], bfr1[kb], acc1, 0, 0, 0);
      }
      int col0 = ncol + l16;
      float bz0 = in_b[col0], bz1 = in_b[col0 + 16];
#pragma unroll
      for (int r = 0; r < 4; ++r) {
        int row = quad * 4 + r;
        xz_s[row][col0]      = f2bf(acc0[r] + bz0);
        xz_s[row][col0 + 16] = f2bf(acc1[r] + bz1);
      }
    }
  }
  __syncthreads();

  // ---- Phase 3: conv+silu -> y=D*xc -> LN_E -> v = yln*silu(z); v overwrites
  //      z-half of row m+1 (same-thread read-before-write). Dead rows -> 0. ----
  {
    const int e0 = lane * 4;
    float w0[4], w1[4], w2[4], cbv[4], Dv[4], gv[4], bv[4];
#pragma unroll
    for (int j = 0; j < 4; ++j) {
      w0[j] = cw[(e0 + j) * 3 + 0];
      w1[j] = cw[(e0 + j) * 3 + 1];
      w2[j] = cw[(e0 + j) * 3 + 2];
      cbv[j] = cb[e0 + j]; Dv[j] = D_p[e0 + j];
      gv[j] = ig[e0 + j];  bv[j] = ib[e0 + j];
    }
#pragma unroll
    for (int j = 0; j < 4; ++j) {
      int m = wid * 4 + j;          // 0..15
      int l = l0 + m;
      int mr = min(m, CHUNK - 1);   // clamp reads (rows <= 15)
      int lr = l0 + mr;
      bool hasL = (lr >= 1), hasR = (lr + 1 < L_);
      short4_t sm1 = *(const short4_t*)&xz_s[mr][e0];
      short4_t s0  = *(const short4_t*)&xz_s[mr + 1][e0];
      short4_t sp1 = *(const short4_t*)&xz_s[mr + 2][e0];
      short4_t sz  = *(const short4_t*)&xz_s[mr + 1][256 + e0];
      float y[4], part = 0.f;
#pragma unroll
      for (int jj = 0; jj < 4; ++jj) {
        float xm1 = hasL ? bf2f(sm1[jj]) : 0.f;
        float x0  = bf2f(s0[jj]);
        float xp1 = hasR ? bf2f(sp1[jj]) : 0.f;
        float cv = w0[jj] * xm1 + w1[jj] * x0 + w2[jj] * xp1 + cbv[jj];
        float sv = cv / (1.f + __expf(-cv));
        y[jj] = Dv[jj] * sv;
        part += y[jj];
      }
      float mean = wave_sum64(part) * (1.f / 256.f);
      float vp = 0.f;
#pragma unroll
      for (int jj = 0; jj < 4; ++jj) { y[jj] -= mean; vp += y[jj] * y[jj]; }
      float rs = rsqrtf(wave_sum64(vp) * (1.f / 256.f) + 1e-5f);
      short4_t outv;
#pragma unroll
      for (int jj = 0; jj < 4; ++jj) {
        float yln = y[jj] * rs * gv[jj] + bv[jj];
        float z = bf2f(sz[jj]);
        outv[jj] = f2bf(yln * (z / (1.f + __expf(-z))));
      }
      if (m >= CHUNK || l >= L_) outv = short4_t{0, 0, 0, 0};
      *(short4_t*)&xz_s[m + 1][256 + e0] = outv;  // v[m] -> z-half row m+1
    }
  }
  __syncthreads();

  // ---- Phase 4: out = v @ wto^T + out_b; x' = (x + out)*mask.
  //      Wave w owns cols [w*32, w*32+32). ----
  {
    short8 vfr[8];
#pragma unroll
    for (int kb = 0; kb < 8; ++kb)
      vfr[kb] = *(const short8*)&xz_s[l16 + 1][256 + kb * 32 + quad * 8];
#pragma unroll
    for (int sn = 0; sn < 2; ++sn) {
      int col = wid * 32 + sn * 16 + l16;
      f32x4 acc = {0.f, 0.f, 0.f, 0.f};
#pragma unroll
      for (int kb = 0; kb < 8; ++kb) {
        short8 bf = *(const short8*)&wtog[(size_t)col * 256 + kb * 32 + quad * 8];
        acc = __builtin_amdgcn_mfma_f32_16x16x32_bf16(vfr[kb], bf, acc, 0, 0, 0);
      }
      float bz = out_b[col];
#pragma unroll
      for (int r = 0; r < 4; ++r) {
        int m = quad * 4 + r;
        int l = l0 + m;
        if (m < CHUNK && l < L_) {
          size_t gi = ((size_t)b * L_ + l) * H_ + col;
          int idx = seqs[b * L_ + l];
          float msk = (idx != 0) ? 1.f : 0.f;
          float xv;
          if (EMBED) {
            xv = (idx != 0) ? (emb[(size_t)idx * H_ + col] + pos[(size_t)l * H_ + col]) : 0.f;
          } else {
            xv = xin[gi];
          }
          xout[gi] = (xv + acc[r] + bz) * msk;
        }
      }
    }
  }
}

// Fused final-LN + logits: each block p=(b,k) recomputes LN of x[b,L-1] (one
// wave) and dots with item_emb[idxs[p]].
__global__ void logits_kernel(const float* __restrict__ x, const float* __restrict__ fg,
                              const float* __restrict__ fb, const int* __restrict__ idxs,
                              const float* __restrict__ emb, float* __restrict__ out) {
  int p = blockIdx.x;  // b*K + k
  int b = p / K_;
  int t = threadIdx.x;  // 64
  size_t r = (size_t)b * L_ + (L_ - 1);
  float v0 = x[r * H_ + t];
  float v1 = x[r * H_ + 64 + t];
  float mean = wave_sum64(v0 + v1) * (1.f / 128.f);
  float d0 = v0 - mean, d1 = v1 - mean;
  float var = wave_sum64(d0 * d0 + d1 * d1) * (1.f / 128.f);
  float rs = rsqrtf(var + 1e-5f);
  float xf0 = d0 * rs * fg[t] + fb[t];
  float xf1 = d1 * rs * fg[64 + t] + fb[64 + t];
  int id = idxs[p];
  float a = xf0 * emb[(size_t)id * H_ + t] + xf1 * emb[(size_t)id * H_ + 64 + t];
  a = wave_sum64(a);
  if (t == 0) out[p] = a;
}

extern "C" void kernel_launch(void* const* d_in, const int* in_sizes, int n_in,
                              void* d_out, int out_size, void* d_ws, size_t ws_size,
                              hipStream_t stream) {
  const int*   seqs   = (const int*)d_in[0];
  const int*   idxs   = (const int*)d_in[1];
  const float* emb    = (const float*)d_in[2];
  const float* pos    = (const float*)d_in[3];
  const float* blk_g  = (const float*)d_in[4];
  const float* blk_b  = (const float*)d_in[5];
  const float* in_w   = (const float*)d_in[6];
  const float* in_b   = (const float*)d_in[7];
  const float* conv_w = (const float*)d_in[8];
  const float* conv_b = (const float*)d_in[9];
  // d_in[10..12] (xproj_w, xproj_b, A_log) feed only the scan term, which
  // cancels in the inner LayerNorm — unused.
  const float* D_p    = (const float*)d_in[13];
  const float* out_w  = (const float*)d_in[14];
  const float* out_b  = (const float*)d_in[15];
  const float* ig     = (const float*)d_in[16];
  const float* ib     = (const float*)d_in[17];
  const float* fg     = (const float*)d_in[18];
  const float* fb     = (const float*)d_in[19];
  float* out = (float*)d_out;
  float* ws = (float*)d_ws;

  // workspace (float units): x, x2 ping-pong; bf16 weights. ~13.4 MB
  float*           x   = ws;                                 // [12800,128] (layer1 out)
  float*           x2  = ws + 1638400;                       // [12800,128] (layer0 out)
  __hip_bfloat16*  wti = (__hip_bfloat16*)(ws + 3276800);    // [2,512,128] bf16
  __hip_bfloat16*  wto = (__hip_bfloat16*)(ws + 3342336);    // [2,128,256] bf16

  wtrans_kernel<<<48, 256, 0, stream>>>(in_w, out_w, wti, wto);

  // layer 0: embed fused (reads seqs/emb/pos), writes x2
  mamba_fused_kernel<1><<<B_ * NCH, 256, 0, stream>>>(
      nullptr, x2, seqs, emb, pos,
      wti, wto, blk_g, blk_b, in_b,
      conv_w, conv_b, D_p, ig, ib, out_b);

  // layer 1: reads x2, writes x
  mamba_fused_kernel<0><<<B_ * NCH, 256, 0, stream>>>(
      x2, x, seqs, emb, pos,
      wti + (size_t)512 * 128, wto + (size_t)128 * 256,
      blk_g + H_, blk_b + H_, in_b + 512,
      conv_w + E_ * 3, conv_b + E_, D_p + E_, ig + E_, ib + E_, out_b + H_);

  logits_kernel<<<B_ * K_, 64, 0, stream>>>(x, fg, fb, idxs, emb, out);
}